// Round 5
// baseline (807.100 us; speedup 1.0000x reference)
//
#include <hip/hip_runtime.h>
#include <cstdint>

#define NPTS 65536
#define NS 16
#define EPSV 1e-5f

typedef __attribute__((ext_vector_type(8))) short bf16x8;
typedef __attribute__((ext_vector_type(4))) float f32x4;
typedef __attribute__((ext_vector_type(4))) unsigned int u32x4;
union FragU { u32x4 u; bf16x8 h; };

// per-layer stats block (512 floats each)
#define SUM1 0
#define SSQ1 64
#define SUM2 128
#define SSQ2 192
#define SUM3 256
#define SSQ3 320
// wfold region (floats)
#define WKAOF 0
#define WQBAOF 4096
#define BKAOF 8192
#define BQBAOF 8256
#define WFOLD_FLOATS 8320

// truncation split of two floats into packed bf16 hi-pair / lo-pair (v_perm based).
__device__ __forceinline__ void split2(float e0, float e1, unsigned int& hi, unsigned int& lo) {
    unsigned int u0 = __float_as_uint(e0), u1 = __float_as_uint(e1);
    hi = __builtin_amdgcn_perm(u1, u0, 0x07060302u);
    float l0f = e0 - __uint_as_float(u0 & 0xFFFF0000u);
    float l1f = e1 - __uint_as_float(u1 & 0xFFFF0000u);
    lo = __builtin_amdgcn_perm(__float_as_uint(l1f), __float_as_uint(l0f), 0x07060302u);
}

__global__ void k_mask(const uint32_t* emp32, uint8_t* mask) {
    int bad = 0;
    for (int w = threadIdx.x; w < 1024; w += 256) bad |= (emp32[w] > 1u) ? 1 : 0;
    __shared__ int sbad[4];
    unsigned long long b = __ballot(bad != 0);
    if ((threadIdx.x & 63) == 0) sbad[threadIdx.x >> 6] = (b != 0ull) ? 1 : 0;
    __syncthreads();
    int flag = sbad[0] | sbad[1] | sbad[2] | sbad[3];
    int i = blockIdx.x * 256 + threadIdx.x;
    uint8_t mv;
    if (flag) mv = (((const uint8_t*)emp32)[i] != 0);
    else      mv = (emp32[i] != 0u);
    mask[i] = mv;
}

// Folded weights: Wka = wk @ A, Wqba = wq @ (B-A); biases likewise.
__global__ void k0(const float* wq, const float* bq, const float* wk, const float* bk,
                   const float* w1, float* wfold, int cin) {
    int f = threadIdx.x;
    int c = blockIdx.x;
    float a = 0.f, q = 0.f;
    for (int d = 0; d < 64; d++) {
        float A  = w1[d*64 + f];
        float Bm = w1[(67+d)*64 + f] - A;
        a = fmaf(wk[c*64 + d], A,  a);
        q = fmaf(wq[c*64 + d], Bm, q);
    }
    wfold[WKAOF  + c*64 + f] = a;
    wfold[WQBAOF + c*64 + f] = q;
    if (c == 0) {
        float ba = 0.f, bqv = 0.f;
        for (int d = 0; d < 64; d++) {
            float A  = w1[d*64 + f];
            float Bm = w1[(67+d)*64 + f] - A;
            ba  = fmaf(bk[d], A,  ba);
            bqv = fmaf(bq[d], Bm, bqv);
        }
        wfold[BKAOF  + f] = ba;
        wfold[BQBAOF + f] = bqv;
    }
}

// MFMA k1: [KA|QBA](n,128) = prebn(feats) @ Wcat(cin,128) + xyz @ Axyz(3,128) + bias.
template<int CIN, bool PREBN>
__global__ void __launch_bounds__(256) k1m(const float* __restrict__ feats, const float* __restrict__ xyz,
                    const float* __restrict__ w1, const float* __restrict__ wfold,
                    const float* __restrict__ statsPrev, const float* __restrict__ goP,
                    const float* __restrict__ boP,
                    float* __restrict__ KA, float* __restrict__ QBA) {
    const int l = threadIdx.x & 63;
    const int wv = threadIdx.x >> 6;
    const int sidx = l & 15;
    const int g = l >> 4;
    const int col = sidx;
    constexpr int NT = (CIN == 64) ? 2 : 1;

    unsigned int bh[NT][2][4], bl[NT][2][4];
    #pragma unroll
    for (int t = 0; t < NT; t++)
    #pragma unroll
    for (int fl = 0; fl < 2; fl++) {
        int f128 = (wv*2 + fl)*16 + col;
        const float* W = (f128 < 64) ? (wfold + WKAOF) : (wfold + WQBAOF);
        int f = (f128 < 64) ? f128 : f128 - 64;
        #pragma unroll
        for (int r = 0; r < 4; r++) {
            int c0 = t*32 + g*8 + 2*r;
            float e0 = 0.f, e1 = 0.f;
            if (CIN == 64 || g < 2) {
                e0 = W[c0*64 + f];
                e1 = W[(c0+1)*64 + f];
            }
            split2(e0, e1, bh[t][fl][r], bl[t][fl][r]);
        }
    }
    unsigned int xbh[2][4], xbl[2][4];
    float biasf[2];
    #pragma unroll
    for (int fl = 0; fl < 2; fl++) {
        int f128 = (wv*2 + fl)*16 + col;
        float A0, A1, A2;
        if (f128 < 64) {
            A0 = w1[64*64 + f128]; A1 = w1[65*64 + f128]; A2 = w1[66*64 + f128];
            biasf[fl] = wfold[BKAOF + f128];
        } else {
            int f = f128 - 64;
            A0 = w1[131*64 + f] - w1[64*64 + f];
            A1 = w1[132*64 + f] - w1[65*64 + f];
            A2 = w1[133*64 + f] - w1[66*64 + f];
            biasf[fl] = wfold[BQBAOF + f];
        }
        split2(A0, A1, xbh[fl][0], xbl[fl][0]);
        split2(A2, 0.f, xbh[fl][1], xbl[fl][1]);
        xbh[fl][2] = 0; xbh[fl][3] = 0; xbl[fl][2] = 0; xbl[fl][3] = 0;
    }
    float scP[NT*8], shP[NT*8];
    if (PREBN) {
        const float invN = 1.0f / (float)NPTS;
        #pragma unroll
        for (int t = 0; t < NT; t++)
        #pragma unroll
        for (int i = 0; i < 8; i++) {
            int c = t*32 + g*8 + i;
            float m = statsPrev[SUM3 + c] * invN;
            float v = fmaxf(statsPrev[SSQ3 + c] * invN - m*m, 0.0f);
            float s = goP[c] * rsqrtf(v + EPSV);
            scP[t*8+i] = s;
            shP[t*8+i] = fmaf(-m, s, boP[c]);
        }
    }

    for (int tile = blockIdx.x; tile < NPTS/16; tile += gridDim.x) {
        int p = tile*16 + sidx;
        unsigned int ahu[NT][4], alu[NT][4];
        #pragma unroll
        for (int t = 0; t < NT; t++) {
            float xv[8];
            if (CIN == 64) {
                f32x4 a0 = *(const f32x4*)(feats + (size_t)p*64 + t*32 + g*8);
                f32x4 a1 = *(const f32x4*)(feats + (size_t)p*64 + t*32 + g*8 + 4);
                #pragma unroll
                for (int i = 0; i < 4; i++) { xv[i] = a0[i]; xv[4+i] = a1[i]; }
                if (PREBN) {
                    #pragma unroll
                    for (int i = 0; i < 8; i++)
                        xv[i] = fmaxf(fmaf(scP[t*8+i], xv[i], shP[t*8+i]), 0.0f);
                }
            } else {
                if (g < 2) {
                    f32x4 a0 = *(const f32x4*)(feats + (size_t)p*16 + g*8);
                    f32x4 a1 = *(const f32x4*)(feats + (size_t)p*16 + g*8 + 4);
                    #pragma unroll
                    for (int i = 0; i < 4; i++) { xv[i] = a0[i]; xv[4+i] = a1[i]; }
                } else {
                    #pragma unroll
                    for (int i = 0; i < 8; i++) xv[i] = 0.f;
                }
            }
            #pragma unroll
            for (int r = 0; r < 4; r++) split2(xv[2*r], xv[2*r+1], ahu[t][r], alu[t][r]);
        }
        unsigned int xah[4] = {0,0,0,0}, xal[4] = {0,0,0,0};
        if (g == 0) {
            float x0 = xyz[p*3], x1 = xyz[p*3+1], x2 = xyz[p*3+2];
            split2(x0, x1, xah[0], xal[0]);
            split2(x2, 0.f, xah[1], xal[1]);
        }
        f32x4 acc[2];
        #pragma unroll
        for (int fl = 0; fl < 2; fl++)
            acc[fl] = (f32x4){biasf[fl], biasf[fl], biasf[fl], biasf[fl]};
        #pragma unroll
        for (int t = 0; t < NT; t++) {
            FragU ah, al;
            ah.u = (u32x4){ahu[t][0], ahu[t][1], ahu[t][2], ahu[t][3]};
            al.u = (u32x4){alu[t][0], alu[t][1], alu[t][2], alu[t][3]};
            #pragma unroll
            for (int fl = 0; fl < 2; fl++) {
                FragU Bh, Bl;
                Bh.u = (u32x4){bh[t][fl][0], bh[t][fl][1], bh[t][fl][2], bh[t][fl][3]};
                Bl.u = (u32x4){bl[t][fl][0], bl[t][fl][1], bl[t][fl][2], bl[t][fl][3]};
                acc[fl] = __builtin_amdgcn_mfma_f32_16x16x32_bf16(ah.h, Bh.h, acc[fl], 0, 0, 0);
                acc[fl] = __builtin_amdgcn_mfma_f32_16x16x32_bf16(ah.h, Bl.h, acc[fl], 0, 0, 0);
                acc[fl] = __builtin_amdgcn_mfma_f32_16x16x32_bf16(al.h, Bh.h, acc[fl], 0, 0, 0);
            }
        }
        {
            FragU ah, al;
            ah.u = (u32x4){xah[0], xah[1], xah[2], xah[3]};
            al.u = (u32x4){xal[0], xal[1], xal[2], xal[3]};
            #pragma unroll
            for (int fl = 0; fl < 2; fl++) {
                FragU Bh, Bl;
                Bh.u = (u32x4){xbh[fl][0], xbh[fl][1], xbh[fl][2], xbh[fl][3]};
                Bl.u = (u32x4){xbl[fl][0], xbl[fl][1], xbl[fl][2], xbl[fl][3]};
                acc[fl] = __builtin_amdgcn_mfma_f32_16x16x32_bf16(ah.h, Bh.h, acc[fl], 0, 0, 0);
                acc[fl] = __builtin_amdgcn_mfma_f32_16x16x32_bf16(ah.h, Bl.h, acc[fl], 0, 0, 0);
                acc[fl] = __builtin_amdgcn_mfma_f32_16x16x32_bf16(al.h, Bh.h, acc[fl], 0, 0, 0);
            }
        }
        #pragma unroll
        for (int fl = 0; fl < 2; fl++) {
            int f128 = (wv*2 + fl)*16 + col;
            #pragma unroll
            for (int r = 0; r < 4; r++) {
                int po = tile*16 + g*4 + r;
                float v = acc[fl][r];
                if (f128 < 64) KA[(size_t)po*64 + f128] = v;
                else           QBA[(size_t)po*64 + (f128-64)] = v;
            }
        }
    }
}

// k2: stats of y1 over (n,s), j-BLOCKED for L2 residency.
// 8 passes over j-blocks of 8192 rows (2 MB); each pair active in exactly one pass.
__global__ void __launch_bounds__(256) k2(const float* __restrict__ KA, const float* __restrict__ QBA,
                   const int* __restrict__ knn, const uint8_t* __restrict__ mask, float* stats) {
    const int l = threadIdx.x & 63;
    const int wv = threadIdx.x >> 6;
    const int s = l & 15;
    const int g = l >> 4;
    float s0[16], s1[16];
    #pragma unroll
    for (int i = 0; i < 16; i++) { s0[i] = 0.f; s1[i] = 0.f; }

    const int STR = gridDim.x * 4;
    for (int b = 0; b < 8; b++) {
        for (int n = blockIdx.x * 4 + wv; n < NPTS; n += STR) {
            if (mask[n]) continue;
            int j = knn[n*16 + s];
            if ((j >> 13) != b) continue;      // per-lane exec mask
            const float* kap = KA + (size_t)j*64 + g*16;
            const float* qbp = QBA + (size_t)n*64 + g*16;
            #pragma unroll
            for (int q = 0; q < 4; q++) {
                f32x4 ka = *(const f32x4*)(kap + q*4);
                f32x4 qb = *(const f32x4*)(qbp + q*4);
                #pragma unroll
                for (int e = 0; e < 4; e++) {
                    float y = ka[e] + qb[e];
                    s0[q*4+e] += y;
                    s1[q*4+e] = fmaf(y, y, s1[q*4+e]);
                }
            }
        }
    }
    #pragma unroll
    for (int i = 0; i < 16; i++) {
        #pragma unroll
        for (int d = 1; d < 16; d <<= 1) {
            s0[i] += __shfl_xor(s0[i], d, 64);
            s1[i] += __shfl_xor(s1[i], d, 64);
        }
    }
    __shared__ float r0[4][64], r1[4][64];
    if (s == 0) {
        #pragma unroll
        for (int i = 0; i < 16; i++) { r0[wv][g*16+i] = s0[i]; r1[wv][g*16+i] = s1[i]; }
    }
    __syncthreads();
    int tid = threadIdx.x;
    if (tid < 64) {
        atomicAdd(&stats[SUM1 + tid], r0[0][tid]+r0[1][tid]+r0[2][tid]+r0[3][tid]);
        atomicAdd(&stats[SSQ1 + tid], r1[0][tid]+r1[1][tid]+r1[2][tid]+r1[3][tid]);
    }
}

// MFMA k4 (round-2 structure, known-good): gather -> bn1+relu -> x1 @ w2, stats2 + max/min.
__global__ void __launch_bounds__(256) k4(const float* KA, const float* QBA, const int* knn,
                   const uint8_t* mask, const float* w2, const float* g1, const float* b1,
                   float* stats, float* y2max, float* y2min) {
    const int l    = threadIdx.x & 63;
    const int wv   = threadIdx.x >> 6;
    const int sidx = l & 15;
    const int g    = l >> 4;
    const int col  = sidx;

    float sc1v[16], sh1v[16];
    const float inv = 1.0f / ((float)NPTS * (float)NS);
    #pragma unroll
    for (int t = 0; t < 2; t++)
    #pragma unroll
    for (int i = 0; i < 8; i++) {
        int c = t*32 + g*8 + i;
        float m = stats[SUM1 + c] * inv;
        float v = fmaxf(stats[SSQ1 + c] * inv - m*m, 0.0f);
        float s = g1[c] * rsqrtf(v + EPSV);
        sc1v[t*8+i] = s;
        sh1v[t*8+i] = fmaf(-m, s, b1[c]);
    }

    unsigned int whu[2][4][4], wlu[2][4][4];
    #pragma unroll
    for (int t = 0; t < 2; t++)
    #pragma unroll
    for (int ft = 0; ft < 4; ft++)
    #pragma unroll
    for (int r = 0; r < 4; r++) {
        int k0i = t*32 + g*8 + 2*r;
        float e0 = w2[k0i*64 + ft*16 + col];
        float e1 = w2[(k0i+1)*64 + ft*16 + col];
        split2(e0, e1, whu[t][ft][r], wlu[t][ft][r]);
    }

    float s0t[4] = {0.f,0.f,0.f,0.f};
    float s1t[4] = {0.f,0.f,0.f,0.f};

    for (int n = blockIdx.x * 4 + wv; n < NPTS; n += gridDim.x * 4) {
        bool masked = mask[n] != 0;
        int j = knn[n*16 + sidx];

        f32x4 kaA = *(const f32x4*)(KA + (size_t)j*64 + g*8);
        f32x4 kaB = *(const f32x4*)(KA + (size_t)j*64 + g*8 + 4);
        f32x4 kaC = *(const f32x4*)(KA + (size_t)j*64 + 32 + g*8);
        f32x4 kaD = *(const f32x4*)(KA + (size_t)j*64 + 32 + g*8 + 4);
        f32x4 qA  = *(const f32x4*)(QBA + (size_t)n*64 + g*8);
        f32x4 qB  = *(const f32x4*)(QBA + (size_t)n*64 + g*8 + 4);
        f32x4 qC  = *(const f32x4*)(QBA + (size_t)n*64 + 32 + g*8);
        f32x4 qD  = *(const f32x4*)(QBA + (size_t)n*64 + 32 + g*8 + 4);

        float x[16];
        #pragma unroll
        for (int i = 0; i < 4; i++) {
            float y0 = masked ? 0.f : (kaA[i] + qA[i]);
            float y1 = masked ? 0.f : (kaB[i] + qB[i]);
            float y2 = masked ? 0.f : (kaC[i] + qC[i]);
            float y3 = masked ? 0.f : (kaD[i] + qD[i]);
            x[i]    = fmaxf(fmaf(sc1v[i],    y0, sh1v[i]),    0.0f);
            x[4+i]  = fmaxf(fmaf(sc1v[4+i],  y1, sh1v[4+i]),  0.0f);
            x[8+i]  = fmaxf(fmaf(sc1v[8+i],  y2, sh1v[8+i]),  0.0f);
            x[12+i] = fmaxf(fmaf(sc1v[12+i], y3, sh1v[12+i]), 0.0f);
        }

        unsigned int ahu[2][4], alu[2][4];
        #pragma unroll
        for (int t = 0; t < 2; t++)
        #pragma unroll
        for (int r = 0; r < 4; r++)
            split2(x[t*8 + 2*r], x[t*8 + 2*r + 1], ahu[t][r], alu[t][r]);

        f32x4 acc[4];
        #pragma unroll
        for (int ft = 0; ft < 4; ft++) acc[ft] = (f32x4){0.f,0.f,0.f,0.f};

        #pragma unroll
        for (int t = 0; t < 2; t++) {
            FragU ah, al;
            ah.u = (u32x4){ahu[t][0], ahu[t][1], ahu[t][2], ahu[t][3]};
            al.u = (u32x4){alu[t][0], alu[t][1], alu[t][2], alu[t][3]};
            #pragma unroll
            for (int ft = 0; ft < 4; ft++) {
                FragU bhf, blf;
                bhf.u = (u32x4){whu[t][ft][0], whu[t][ft][1], whu[t][ft][2], whu[t][ft][3]};
                blf.u = (u32x4){wlu[t][ft][0], wlu[t][ft][1], wlu[t][ft][2], wlu[t][ft][3]};
                acc[ft] = __builtin_amdgcn_mfma_f32_16x16x32_bf16(ah.h, bhf.h, acc[ft], 0, 0, 0);
                acc[ft] = __builtin_amdgcn_mfma_f32_16x16x32_bf16(ah.h, blf.h, acc[ft], 0, 0, 0);
                acc[ft] = __builtin_amdgcn_mfma_f32_16x16x32_bf16(al.h, bhf.h, acc[ft], 0, 0, 0);
            }
        }

        float tmax[4], tmin[4];
        #pragma unroll
        for (int ft = 0; ft < 4; ft++) {
            f32x4 d = acc[ft];
            float lmax = fmaxf(fmaxf(d[0], d[1]), fmaxf(d[2], d[3]));
            float lmin = fminf(fminf(d[0], d[1]), fminf(d[2], d[3]));
            s0t[ft] += (d[0] + d[1]) + (d[2] + d[3]);
            s1t[ft] += fmaf(d[0],d[0], fmaf(d[1],d[1], fmaf(d[2],d[2], d[3]*d[3])));
            lmax = fmaxf(lmax, __shfl_xor(lmax, 16, 64));
            lmax = fmaxf(lmax, __shfl_xor(lmax, 32, 64));
            lmin = fminf(lmin, __shfl_xor(lmin, 16, 64));
            lmin = fminf(lmin, __shfl_xor(lmin, 32, 64));
            tmax[ft] = lmax; tmin[ft] = lmin;
        }
        float mx = (g==0) ? tmax[0] : (g==1) ? tmax[1] : (g==2) ? tmax[2] : tmax[3];
        float mn = (g==0) ? tmin[0] : (g==1) ? tmin[1] : (g==2) ? tmin[2] : tmin[3];
        y2max[(size_t)n*64 + l] = mx;
        y2min[(size_t)n*64 + l] = mn;
    }

    #pragma unroll
    for (int ft = 0; ft < 4; ft++) {
        s0t[ft] += __shfl_xor(s0t[ft], 16, 64);
        s0t[ft] += __shfl_xor(s0t[ft], 32, 64);
        s1t[ft] += __shfl_xor(s1t[ft], 16, 64);
        s1t[ft] += __shfl_xor(s1t[ft], 32, 64);
    }
    float myS0 = (g==0) ? s0t[0] : (g==1) ? s0t[1] : (g==2) ? s0t[2] : s0t[3];
    float myS1 = (g==0) ? s1t[0] : (g==1) ? s1t[1] : (g==2) ? s1t[2] : s1t[3];
    __shared__ float red[8][64];
    red[wv][l] = myS0;
    red[4+wv][l] = myS1;
    __syncthreads();
    if (wv == 0) {
        atomicAdd(&stats[SUM2 + l], red[0][l]+red[1][l]+red[2][l]+red[3][l]);
        atomicAdd(&stats[SSQ2 + l], red[4][l]+red[5][l]+red[6][l]+red[7][l]);
    }
}

// MFMA k5: m = relu(bn2(max/min)); y3 = m @ wo; stats3.
__global__ void __launch_bounds__(256) k5m(const float* __restrict__ y2max, const float* __restrict__ y2min,
                    const float* __restrict__ wo, const float* __restrict__ g2, const float* __restrict__ b2,
                    float* stats, float* __restrict__ y3) {
    const int l = threadIdx.x & 63;
    const int wv = threadIdx.x >> 6;
    const int sidx = l & 15;
    const int g = l >> 4;
    const int ft = wv;

    unsigned int bh[2][4], bl[2][4];
    #pragma unroll
    for (int t = 0; t < 2; t++)
    #pragma unroll
    for (int r = 0; r < 4; r++) {
        int c0 = t*32 + g*8 + 2*r;
        split2(wo[c0*64 + ft*16 + sidx], wo[(c0+1)*64 + ft*16 + sidx], bh[t][r], bl[t][r]);
    }
    float sc2v[16], sh2v[16];
    const float inv = 1.0f / ((float)NPTS * (float)NS);
    #pragma unroll
    for (int t = 0; t < 2; t++)
    #pragma unroll
    for (int i = 0; i < 8; i++) {
        int c = t*32 + g*8 + i;
        float m = stats[SUM2 + c] * inv;
        float v = fmaxf(stats[SSQ2 + c] * inv - m*m, 0.0f);
        float s = g2[c] * rsqrtf(v + EPSV);
        sc2v[t*8+i] = s;
        sh2v[t*8+i] = fmaf(-m, s, b2[c]);
    }
    float s0a = 0.f, s1a = 0.f;
    for (int tile = blockIdx.x; tile < NPTS/16; tile += gridDim.x) {
        int p = tile*16 + sidx;
        unsigned int ahu[2][4], alu[2][4];
        #pragma unroll
        for (int t = 0; t < 2; t++) {
            f32x4 mx0 = *(const f32x4*)(y2max + (size_t)p*64 + t*32 + g*8);
            f32x4 mx1 = *(const f32x4*)(y2max + (size_t)p*64 + t*32 + g*8 + 4);
            f32x4 mn0 = *(const f32x4*)(y2min + (size_t)p*64 + t*32 + g*8);
            f32x4 mn1 = *(const f32x4*)(y2min + (size_t)p*64 + t*32 + g*8 + 4);
            float mval[8];
            #pragma unroll
            for (int i = 0; i < 4; i++) {
                float sc = sc2v[t*8+i];
                float pre = (sc >= 0.f) ? mx0[i] : mn0[i];
                mval[i] = fmaxf(fmaf(sc, pre, sh2v[t*8+i]), 0.0f);
                float sc2 = sc2v[t*8+4+i];
                float pre2 = (sc2 >= 0.f) ? mx1[i] : mn1[i];
                mval[4+i] = fmaxf(fmaf(sc2, pre2, sh2v[t*8+4+i]), 0.0f);
            }
            #pragma unroll
            for (int r = 0; r < 4; r++) split2(mval[2*r], mval[2*r+1], ahu[t][r], alu[t][r]);
        }
        f32x4 acc = (f32x4){0.f,0.f,0.f,0.f};
        #pragma unroll
        for (int t = 0; t < 2; t++) {
            FragU ah, al, Bh, Bl;
            ah.u = (u32x4){ahu[t][0], ahu[t][1], ahu[t][2], ahu[t][3]};
            al.u = (u32x4){alu[t][0], alu[t][1], alu[t][2], alu[t][3]};
            Bh.u = (u32x4){bh[t][0], bh[t][1], bh[t][2], bh[t][3]};
            Bl.u = (u32x4){bl[t][0], bl[t][1], bl[t][2], bl[t][3]};
            acc = __builtin_amdgcn_mfma_f32_16x16x32_bf16(ah.h, Bh.h, acc, 0, 0, 0);
            acc = __builtin_amdgcn_mfma_f32_16x16x32_bf16(ah.h, Bl.h, acc, 0, 0, 0);
            acc = __builtin_amdgcn_mfma_f32_16x16x32_bf16(al.h, Bh.h, acc, 0, 0, 0);
        }
        #pragma unroll
        for (int r = 0; r < 4; r++) {
            int po = tile*16 + g*4 + r;
            float v = acc[r];
            y3[(size_t)po*64 + ft*16 + sidx] = v;
            s0a += v;
            s1a = fmaf(v, v, s1a);
        }
    }
    s0a += __shfl_xor(s0a, 16, 64); s0a += __shfl_xor(s0a, 32, 64);
    s1a += __shfl_xor(s1a, 16, 64); s1a += __shfl_xor(s1a, 32, 64);
    __shared__ float r0[64], r1[64];
    if (l < 16) { r0[wv*16 + sidx] = s0a; r1[wv*16 + sidx] = s1a; }
    __syncthreads();
    int tid = threadIdx.x;
    if (tid < 64) {
        atomicAdd(&stats[SUM3 + tid], r0[tid]);
        atomicAdd(&stats[SSQ3 + tid], r1[tid]);
    }
}

// final: out = relu(bn3(y3)) in-place (layer 1 only).
__global__ void k6(float* y3, const float* stats, const float* go, const float* bo) {
    int i = blockIdx.x * 256 + threadIdx.x;
    int f = i & 63;
    const float inv = 1.0f / (float)NPTS;
    float m = stats[SUM3 + f] * inv;
    float v = fmaxf(stats[SSQ3 + f] * inv - m*m, 0.0f);
    float s = go[f] * rsqrtf(v + EPSV);
    float sh = fmaf(-m, s, bo[f]);
    y3[i] = fmaxf(fmaf(s, y3[i], sh), 0.0f);
}

extern "C" void kernel_launch(void* const* d_in, const int* in_sizes, int n_in,
                              void* d_out, int out_size, void* d_ws, size_t ws_size,
                              hipStream_t stream) {
    const float* xyz    = (const float*)d_in[0];
    const float* feats0 = (const float*)d_in[1];
    const int*   knn    = (const int*)d_in[2];
    const void*  empty  = d_in[3];
    float* ws = (float*)d_ws;
    const size_t N64 = (size_t)NPTS * 64;
    float* KA    = ws;
    float* QBA   = ws + N64;
    float* Y2MAX = ws + 2*N64;
    float* Y2MIN = ws + 3*N64;
    float* stats = ws + 4*N64;           // 2 x 512 floats
    float* wfold = stats + 1024;         // WFOLD_FLOATS
    uint8_t* mask = (uint8_t*)(wfold + WFOLD_FLOATS);
    float* out = (float*)d_out;

    hipMemsetAsync(stats, 0, 1024 * sizeof(float), stream);
    k_mask<<<NPTS/256, 256, 0, stream>>>((const uint32_t*)empty, mask);

    const float* const* p0 = (const float* const*)(d_in + 4);
    const float* const* p1 = (const float* const*)(d_in + 4 + 13);

    // ---- layer 0 ----
    {
        const float* const* p = p0;
        float* sl = stats;
        k0<<<16, 64, 0, stream>>>(p[0], p[1], p[2], p[3], p[4], wfold, 16);
        k1m<16, false><<<1024, 256, 0, stream>>>(feats0, xyz, p[4], wfold,
                                                 sl, p[11], p[12], KA, QBA);
        k2<<<2048, 256, 0, stream>>>(KA, QBA, knn, mask, sl);
        k4<<<2048, 256, 0, stream>>>(KA, QBA, knn, mask, p[7], p[5], p[6], sl, Y2MAX, Y2MIN);
        k5m<<<2048, 256, 0, stream>>>(Y2MAX, Y2MIN, p[10], p[8], p[9], sl, out);  // y3_0 -> d_out
    }
    // ---- layer 1 ----
    {
        const float* const* p = p1;
        float* sl = stats + 512;
        k0<<<64, 64, 0, stream>>>(p[0], p[1], p[2], p[3], p[4], wfold, 64);
        k1m<64, true><<<1024, 256, 0, stream>>>(out, xyz, p[4], wfold,
                                                stats, p0[11], p0[12], KA, QBA);
        k2<<<2048, 256, 0, stream>>>(KA, QBA, knn, mask, sl);
        k4<<<2048, 256, 0, stream>>>(KA, QBA, knn, mask, p[7], p[5], p[6], sl, Y2MAX, Y2MIN);
        k5m<<<2048, 256, 0, stream>>>(Y2MAX, Y2MIN, p[10], p[8], p[9], sl, out);  // y3_1 -> d_out
        k6<<<NPTS*64/256, 256, 0, stream>>>(out, sl, p[11], p[12]);               // in-place bn3
    }
}

// Round 6
// 608.907 us; speedup vs baseline: 1.3255x; 1.3255x over previous
//
#include <hip/hip_runtime.h>
#include <cstdint>

#define NPTS 65536
#define NS 16
#define EPSV 1e-5f

typedef __attribute__((ext_vector_type(8))) short bf16x8;
typedef __attribute__((ext_vector_type(4))) float f32x4;
typedef __attribute__((ext_vector_type(4))) unsigned int u32x4;
union FragU { u32x4 u; bf16x8 h; };

// per-layer stats block (512 floats each)
#define SUM1 0
#define SSQ1 64
#define SUM2 128
#define SSQ2 192
#define SUM3 256
#define SSQ3 320
// wfold region (floats)
#define WKAOF 0
#define WQBAOF 4096
#define BKAOF 8192
#define BQBAOF 8256
#define WFOLD_FLOATS 8320

// truncation split of two floats into packed bf16 hi-pair / lo-pair (v_perm based).
__device__ __forceinline__ void split2(float e0, float e1, unsigned int& hi, unsigned int& lo) {
    unsigned int u0 = __float_as_uint(e0), u1 = __float_as_uint(e1);
    hi = __builtin_amdgcn_perm(u1, u0, 0x07060302u);
    float l0f = e0 - __uint_as_float(u0 & 0xFFFF0000u);
    float l1f = e1 - __uint_as_float(u1 & 0xFFFF0000u);
    lo = __builtin_amdgcn_perm(__float_as_uint(l1f), __float_as_uint(l0f), 0x07060302u);
}

__global__ void k_mask(const uint32_t* emp32, uint8_t* mask) {
    int bad = 0;
    for (int w = threadIdx.x; w < 1024; w += 256) bad |= (emp32[w] > 1u) ? 1 : 0;
    __shared__ int sbad[4];
    unsigned long long b = __ballot(bad != 0);
    if ((threadIdx.x & 63) == 0) sbad[threadIdx.x >> 6] = (b != 0ull) ? 1 : 0;
    __syncthreads();
    int flag = sbad[0] | sbad[1] | sbad[2] | sbad[3];
    int i = blockIdx.x * 256 + threadIdx.x;
    uint8_t mv;
    if (flag) mv = (((const uint8_t*)emp32)[i] != 0);
    else      mv = (emp32[i] != 0u);
    mask[i] = mv;
}

// Folded weights: Wka = wk @ A, Wqba = wq @ (B-A); biases likewise.
__global__ void k0(const float* wq, const float* bq, const float* wk, const float* bk,
                   const float* w1, float* wfold, int cin) {
    int f = threadIdx.x;
    int c = blockIdx.x;
    float a = 0.f, q = 0.f;
    for (int d = 0; d < 64; d++) {
        float A  = w1[d*64 + f];
        float Bm = w1[(67+d)*64 + f] - A;
        a = fmaf(wk[c*64 + d], A,  a);
        q = fmaf(wq[c*64 + d], Bm, q);
    }
    wfold[WKAOF  + c*64 + f] = a;
    wfold[WQBAOF + c*64 + f] = q;
    if (c == 0) {
        float ba = 0.f, bqv = 0.f;
        for (int d = 0; d < 64; d++) {
            float A  = w1[d*64 + f];
            float Bm = w1[(67+d)*64 + f] - A;
            ba  = fmaf(bk[d], A,  ba);
            bqv = fmaf(bq[d], Bm, bqv);
        }
        wfold[BKAOF  + f] = ba;
        wfold[BQBAOF + f] = bqv;
    }
}

// MFMA k1: [KA|QBA](n,128) = prebn(feats) @ Wcat(cin,128) + xyz @ Axyz(3,128) + bias.
template<int CIN, bool PREBN>
__global__ void __launch_bounds__(256) k1m(const float* __restrict__ feats, const float* __restrict__ xyz,
                    const float* __restrict__ w1, const float* __restrict__ wfold,
                    const float* __restrict__ statsPrev, const float* __restrict__ goP,
                    const float* __restrict__ boP,
                    float* __restrict__ KA, float* __restrict__ QBA) {
    const int l = threadIdx.x & 63;
    const int wv = threadIdx.x >> 6;
    const int sidx = l & 15;
    const int g = l >> 4;
    const int col = sidx;
    constexpr int NT = (CIN == 64) ? 2 : 1;

    unsigned int bh[NT][2][4], bl[NT][2][4];
    #pragma unroll
    for (int t = 0; t < NT; t++)
    #pragma unroll
    for (int fl = 0; fl < 2; fl++) {
        int f128 = (wv*2 + fl)*16 + col;
        const float* W = (f128 < 64) ? (wfold + WKAOF) : (wfold + WQBAOF);
        int f = (f128 < 64) ? f128 : f128 - 64;
        #pragma unroll
        for (int r = 0; r < 4; r++) {
            int c0 = t*32 + g*8 + 2*r;
            float e0 = 0.f, e1 = 0.f;
            if (CIN == 64 || g < 2) {
                e0 = W[c0*64 + f];
                e1 = W[(c0+1)*64 + f];
            }
            split2(e0, e1, bh[t][fl][r], bl[t][fl][r]);
        }
    }
    unsigned int xbh[2][4], xbl[2][4];
    float biasf[2];
    #pragma unroll
    for (int fl = 0; fl < 2; fl++) {
        int f128 = (wv*2 + fl)*16 + col;
        float A0, A1, A2;
        if (f128 < 64) {
            A0 = w1[64*64 + f128]; A1 = w1[65*64 + f128]; A2 = w1[66*64 + f128];
            biasf[fl] = wfold[BKAOF + f128];
        } else {
            int f = f128 - 64;
            A0 = w1[131*64 + f] - w1[64*64 + f];
            A1 = w1[132*64 + f] - w1[65*64 + f];
            A2 = w1[133*64 + f] - w1[66*64 + f];
            biasf[fl] = wfold[BQBAOF + f];
        }
        split2(A0, A1, xbh[fl][0], xbl[fl][0]);
        split2(A2, 0.f, xbh[fl][1], xbl[fl][1]);
        xbh[fl][2] = 0; xbh[fl][3] = 0; xbl[fl][2] = 0; xbl[fl][3] = 0;
    }
    float scP[NT*8], shP[NT*8];
    if (PREBN) {
        const float invN = 1.0f / (float)NPTS;
        #pragma unroll
        for (int t = 0; t < NT; t++)
        #pragma unroll
        for (int i = 0; i < 8; i++) {
            int c = t*32 + g*8 + i;
            float m = statsPrev[SUM3 + c] * invN;
            float v = fmaxf(statsPrev[SSQ3 + c] * invN - m*m, 0.0f);
            float s = goP[c] * rsqrtf(v + EPSV);
            scP[t*8+i] = s;
            shP[t*8+i] = fmaf(-m, s, boP[c]);
        }
    }

    for (int tile = blockIdx.x; tile < NPTS/16; tile += gridDim.x) {
        int p = tile*16 + sidx;
        unsigned int ahu[NT][4], alu[NT][4];
        #pragma unroll
        for (int t = 0; t < NT; t++) {
            float xv[8];
            if (CIN == 64) {
                f32x4 a0 = *(const f32x4*)(feats + (size_t)p*64 + t*32 + g*8);
                f32x4 a1 = *(const f32x4*)(feats + (size_t)p*64 + t*32 + g*8 + 4);
                #pragma unroll
                for (int i = 0; i < 4; i++) { xv[i] = a0[i]; xv[4+i] = a1[i]; }
                if (PREBN) {
                    #pragma unroll
                    for (int i = 0; i < 8; i++)
                        xv[i] = fmaxf(fmaf(scP[t*8+i], xv[i], shP[t*8+i]), 0.0f);
                }
            } else {
                if (g < 2) {
                    f32x4 a0 = *(const f32x4*)(feats + (size_t)p*16 + g*8);
                    f32x4 a1 = *(const f32x4*)(feats + (size_t)p*16 + g*8 + 4);
                    #pragma unroll
                    for (int i = 0; i < 4; i++) { xv[i] = a0[i]; xv[4+i] = a1[i]; }
                } else {
                    #pragma unroll
                    for (int i = 0; i < 8; i++) xv[i] = 0.f;
                }
            }
            #pragma unroll
            for (int r = 0; r < 4; r++) split2(xv[2*r], xv[2*r+1], ahu[t][r], alu[t][r]);
        }
        unsigned int xah[4] = {0,0,0,0}, xal[4] = {0,0,0,0};
        if (g == 0) {
            float x0 = xyz[p*3], x1 = xyz[p*3+1], x2 = xyz[p*3+2];
            split2(x0, x1, xah[0], xal[0]);
            split2(x2, 0.f, xah[1], xal[1]);
        }
        f32x4 acc[2];
        #pragma unroll
        for (int fl = 0; fl < 2; fl++)
            acc[fl] = (f32x4){biasf[fl], biasf[fl], biasf[fl], biasf[fl]};
        #pragma unroll
        for (int t = 0; t < NT; t++) {
            FragU ah, al;
            ah.u = (u32x4){ahu[t][0], ahu[t][1], ahu[t][2], ahu[t][3]};
            al.u = (u32x4){alu[t][0], alu[t][1], alu[t][2], alu[t][3]};
            #pragma unroll
            for (int fl = 0; fl < 2; fl++) {
                FragU Bh, Bl;
                Bh.u = (u32x4){bh[t][fl][0], bh[t][fl][1], bh[t][fl][2], bh[t][fl][3]};
                Bl.u = (u32x4){bl[t][fl][0], bl[t][fl][1], bl[t][fl][2], bl[t][fl][3]};
                acc[fl] = __builtin_amdgcn_mfma_f32_16x16x32_bf16(ah.h, Bh.h, acc[fl], 0, 0, 0);
                acc[fl] = __builtin_amdgcn_mfma_f32_16x16x32_bf16(ah.h, Bl.h, acc[fl], 0, 0, 0);
                acc[fl] = __builtin_amdgcn_mfma_f32_16x16x32_bf16(al.h, Bh.h, acc[fl], 0, 0, 0);
            }
        }
        {
            FragU ah, al;
            ah.u = (u32x4){xah[0], xah[1], xah[2], xah[3]};
            al.u = (u32x4){xal[0], xal[1], xal[2], xal[3]};
            #pragma unroll
            for (int fl = 0; fl < 2; fl++) {
                FragU Bh, Bl;
                Bh.u = (u32x4){xbh[fl][0], xbh[fl][1], xbh[fl][2], xbh[fl][3]};
                Bl.u = (u32x4){xbl[fl][0], xbl[fl][1], xbl[fl][2], xbl[fl][3]};
                acc[fl] = __builtin_amdgcn_mfma_f32_16x16x32_bf16(ah.h, Bh.h, acc[fl], 0, 0, 0);
                acc[fl] = __builtin_amdgcn_mfma_f32_16x16x32_bf16(ah.h, Bl.h, acc[fl], 0, 0, 0);
                acc[fl] = __builtin_amdgcn_mfma_f32_16x16x32_bf16(al.h, Bh.h, acc[fl], 0, 0, 0);
            }
        }
        #pragma unroll
        for (int fl = 0; fl < 2; fl++) {
            int f128 = (wv*2 + fl)*16 + col;
            #pragma unroll
            for (int r = 0; r < 4; r++) {
                int po = tile*16 + g*4 + r;
                float v = acc[fl][r];
                if (f128 < 64) KA[(size_t)po*64 + f128] = v;
                else           QBA[(size_t)po*64 + (f128-64)] = v;
            }
        }
    }
}

// k2: stats of y1 over (n,s). Batch-2 points per wave: both random gathers in
// flight before either compute. lane = (g, s); channels g*16..g*16+15.
__global__ void __launch_bounds__(256) k2(const float* __restrict__ KA, const float* __restrict__ QBA,
                   const int* __restrict__ knn, const uint8_t* __restrict__ mask, float* stats) {
    const int l = threadIdx.x & 63;
    const int wv = threadIdx.x >> 6;
    const int s = l & 15;
    const int g = l >> 4;
    float s0[16], s1[16];
    #pragma unroll
    for (int i = 0; i < 16; i++) { s0[i] = 0.f; s1[i] = 0.f; }

    const int STR = gridDim.x * 8;
    for (int n0 = blockIdx.x * 8 + wv*2; n0 < NPTS; n0 += STR) {
        bool msk[2];
        f32x4 ka[2][4];
        #pragma unroll
        for (int u = 0; u < 2; u++) {
            int n = n0 + u;
            msk[u] = (mask[n] != 0);
            if (!msk[u]) {
                int j = knn[n*16 + s];
                const float* kap = KA + (size_t)j*64 + g*16;
                ka[u][0] = *(const f32x4*)(kap);
                ka[u][1] = *(const f32x4*)(kap + 4);
                ka[u][2] = *(const f32x4*)(kap + 8);
                ka[u][3] = *(const f32x4*)(kap + 12);
            }
        }
        #pragma unroll
        for (int u = 0; u < 2; u++) {
            if (msk[u]) continue;
            int n = n0 + u;
            const float* qbp = QBA + (size_t)n*64 + g*16;
            #pragma unroll
            for (int q = 0; q < 4; q++) {
                f32x4 qb = *(const f32x4*)(qbp + q*4);
                #pragma unroll
                for (int e = 0; e < 4; e++) {
                    float y = ka[u][q][e] + qb[e];
                    s0[q*4+e] += y;
                    s1[q*4+e] = fmaf(y, y, s1[q*4+e]);
                }
            }
        }
    }
    #pragma unroll
    for (int i = 0; i < 16; i++) {
        #pragma unroll
        for (int d = 1; d < 16; d <<= 1) {
            s0[i] += __shfl_xor(s0[i], d, 64);
            s1[i] += __shfl_xor(s1[i], d, 64);
        }
    }
    __shared__ float r0[4][64], r1[4][64];
    if (s == 0) {
        #pragma unroll
        for (int i = 0; i < 16; i++) { r0[wv][g*16+i] = s0[i]; r1[wv][g*16+i] = s1[i]; }
    }
    __syncthreads();
    int tid = threadIdx.x;
    if (tid < 64) {
        atomicAdd(&stats[SUM1 + tid], r0[0][tid]+r0[1][tid]+r0[2][tid]+r0[3][tid]);
        atomicAdd(&stats[SSQ1 + tid], r1[0][tid]+r1[1][tid]+r1[2][tid]+r1[3][tid]);
    }
}

// MFMA k4: batch-2 gather -> bn1+relu -> x1 @ w2 (3-term split), stats2 + max/min.
__global__ void __launch_bounds__(256) k4(const float* __restrict__ KA, const float* __restrict__ QBA,
                   const int* __restrict__ knn, const uint8_t* __restrict__ mask,
                   const float* __restrict__ w2, const float* __restrict__ g1, const float* __restrict__ b1,
                   float* stats, float* __restrict__ y2max, float* __restrict__ y2min) {
    const int l    = threadIdx.x & 63;
    const int wv   = threadIdx.x >> 6;
    const int sidx = l & 15;
    const int g    = l >> 4;
    const int col  = sidx;

    float sc1v[16], sh1v[16];
    const float inv = 1.0f / ((float)NPTS * (float)NS);
    #pragma unroll
    for (int t = 0; t < 2; t++)
    #pragma unroll
    for (int i = 0; i < 8; i++) {
        int c = t*32 + g*8 + i;
        float m = stats[SUM1 + c] * inv;
        float v = fmaxf(stats[SSQ1 + c] * inv - m*m, 0.0f);
        float s = g1[c] * rsqrtf(v + EPSV);
        sc1v[t*8+i] = s;
        sh1v[t*8+i] = fmaf(-m, s, b1[c]);
    }

    unsigned int whu[2][4][4], wlu[2][4][4];
    #pragma unroll
    for (int t = 0; t < 2; t++)
    #pragma unroll
    for (int ft = 0; ft < 4; ft++)
    #pragma unroll
    for (int r = 0; r < 4; r++) {
        int k0i = t*32 + g*8 + 2*r;
        float e0 = w2[k0i*64 + ft*16 + col];
        float e1 = w2[(k0i+1)*64 + ft*16 + col];
        split2(e0, e1, whu[t][ft][r], wlu[t][ft][r]);
    }

    float s0t[4] = {0.f,0.f,0.f,0.f};
    float s1t[4] = {0.f,0.f,0.f,0.f};

    const int STR = gridDim.x * 8;
    for (int n0 = blockIdx.x * 8 + wv*2; n0 < NPTS; n0 += STR) {
        bool msk[2];
        f32x4 ka[2][4];
        #pragma unroll
        for (int u = 0; u < 2; u++) {
            int n = n0 + u;
            msk[u] = (mask[n] != 0);
            int j = knn[n*16 + sidx];
            const float* kap = KA + (size_t)j*64;
            ka[u][0] = *(const f32x4*)(kap + g*8);
            ka[u][1] = *(const f32x4*)(kap + g*8 + 4);
            ka[u][2] = *(const f32x4*)(kap + 32 + g*8);
            ka[u][3] = *(const f32x4*)(kap + 32 + g*8 + 4);
        }
        #pragma unroll
        for (int u = 0; u < 2; u++) {
            int n = n0 + u;
            bool masked = msk[u];
            f32x4 qA = *(const f32x4*)(QBA + (size_t)n*64 + g*8);
            f32x4 qB = *(const f32x4*)(QBA + (size_t)n*64 + g*8 + 4);
            f32x4 qC = *(const f32x4*)(QBA + (size_t)n*64 + 32 + g*8);
            f32x4 qD = *(const f32x4*)(QBA + (size_t)n*64 + 32 + g*8 + 4);

            float x[16];
            #pragma unroll
            for (int i = 0; i < 4; i++) {
                float y0 = masked ? 0.f : (ka[u][0][i] + qA[i]);
                float y1 = masked ? 0.f : (ka[u][1][i] + qB[i]);
                float y2 = masked ? 0.f : (ka[u][2][i] + qC[i]);
                float y3 = masked ? 0.f : (ka[u][3][i] + qD[i]);
                x[i]    = fmaxf(fmaf(sc1v[i],    y0, sh1v[i]),    0.0f);
                x[4+i]  = fmaxf(fmaf(sc1v[4+i],  y1, sh1v[4+i]),  0.0f);
                x[8+i]  = fmaxf(fmaf(sc1v[8+i],  y2, sh1v[8+i]),  0.0f);
                x[12+i] = fmaxf(fmaf(sc1v[12+i], y3, sh1v[12+i]), 0.0f);
            }

            unsigned int ahu[2][4], alu[2][4];
            #pragma unroll
            for (int t = 0; t < 2; t++)
            #pragma unroll
            for (int r = 0; r < 4; r++)
                split2(x[t*8 + 2*r], x[t*8 + 2*r + 1], ahu[t][r], alu[t][r]);

            f32x4 acc[4];
            #pragma unroll
            for (int ft = 0; ft < 4; ft++) acc[ft] = (f32x4){0.f,0.f,0.f,0.f};

            #pragma unroll
            for (int t = 0; t < 2; t++) {
                FragU ah, al;
                ah.u = (u32x4){ahu[t][0], ahu[t][1], ahu[t][2], ahu[t][3]};
                al.u = (u32x4){alu[t][0], alu[t][1], alu[t][2], alu[t][3]};
                #pragma unroll
                for (int ft = 0; ft < 4; ft++) {
                    FragU bhf, blf;
                    bhf.u = (u32x4){whu[t][ft][0], whu[t][ft][1], whu[t][ft][2], whu[t][ft][3]};
                    blf.u = (u32x4){wlu[t][ft][0], wlu[t][ft][1], wlu[t][ft][2], wlu[t][ft][3]};
                    acc[ft] = __builtin_amdgcn_mfma_f32_16x16x32_bf16(ah.h, bhf.h, acc[ft], 0, 0, 0);
                    acc[ft] = __builtin_amdgcn_mfma_f32_16x16x32_bf16(ah.h, blf.h, acc[ft], 0, 0, 0);
                    acc[ft] = __builtin_amdgcn_mfma_f32_16x16x32_bf16(al.h, bhf.h, acc[ft], 0, 0, 0);
                }
            }

            float tmax[4], tmin[4];
            #pragma unroll
            for (int ft = 0; ft < 4; ft++) {
                f32x4 d = acc[ft];
                float lmax = fmaxf(fmaxf(d[0], d[1]), fmaxf(d[2], d[3]));
                float lmin = fminf(fminf(d[0], d[1]), fminf(d[2], d[3]));
                s0t[ft] += (d[0] + d[1]) + (d[2] + d[3]);
                s1t[ft] += fmaf(d[0],d[0], fmaf(d[1],d[1], fmaf(d[2],d[2], d[3]*d[3])));
                lmax = fmaxf(lmax, __shfl_xor(lmax, 16, 64));
                lmax = fmaxf(lmax, __shfl_xor(lmax, 32, 64));
                lmin = fminf(lmin, __shfl_xor(lmin, 16, 64));
                lmin = fminf(lmin, __shfl_xor(lmin, 32, 64));
                tmax[ft] = lmax; tmin[ft] = lmin;
            }
            float mx = (g==0) ? tmax[0] : (g==1) ? tmax[1] : (g==2) ? tmax[2] : tmax[3];
            float mn = (g==0) ? tmin[0] : (g==1) ? tmin[1] : (g==2) ? tmin[2] : tmin[3];
            y2max[(size_t)n*64 + l] = mx;
            y2min[(size_t)n*64 + l] = mn;
        }
    }

    #pragma unroll
    for (int ft = 0; ft < 4; ft++) {
        s0t[ft] += __shfl_xor(s0t[ft], 16, 64);
        s0t[ft] += __shfl_xor(s0t[ft], 32, 64);
        s1t[ft] += __shfl_xor(s1t[ft], 16, 64);
        s1t[ft] += __shfl_xor(s1t[ft], 32, 64);
    }
    float myS0 = (g==0) ? s0t[0] : (g==1) ? s0t[1] : (g==2) ? s0t[2] : s0t[3];
    float myS1 = (g==0) ? s1t[0] : (g==1) ? s1t[1] : (g==2) ? s1t[2] : s1t[3];
    __shared__ float red[8][64];
    red[wv][l] = myS0;
    red[4+wv][l] = myS1;
    __syncthreads();
    if (wv == 0) {
        atomicAdd(&stats[SUM2 + l], red[0][l]+red[1][l]+red[2][l]+red[3][l]);
        atomicAdd(&stats[SSQ2 + l], red[4][l]+red[5][l]+red[6][l]+red[7][l]);
    }
}

// MFMA k5: m = relu(bn2(max/min)); y3 = m @ wo; stats3.
__global__ void __launch_bounds__(256) k5m(const float* __restrict__ y2max, const float* __restrict__ y2min,
                    const float* __restrict__ wo, const float* __restrict__ g2, const float* __restrict__ b2,
                    float* stats, float* __restrict__ y3) {
    const int l = threadIdx.x & 63;
    const int wv = threadIdx.x >> 6;
    const int sidx = l & 15;
    const int g = l >> 4;
    const int ft = wv;

    unsigned int bh[2][4], bl[2][4];
    #pragma unroll
    for (int t = 0; t < 2; t++)
    #pragma unroll
    for (int r = 0; r < 4; r++) {
        int c0 = t*32 + g*8 + 2*r;
        split2(wo[c0*64 + ft*16 + sidx], wo[(c0+1)*64 + ft*16 + sidx], bh[t][r], bl[t][r]);
    }
    float sc2v[16], sh2v[16];
    const float inv = 1.0f / ((float)NPTS * (float)NS);
    #pragma unroll
    for (int t = 0; t < 2; t++)
    #pragma unroll
    for (int i = 0; i < 8; i++) {
        int c = t*32 + g*8 + i;
        float m = stats[SUM2 + c] * inv;
        float v = fmaxf(stats[SSQ2 + c] * inv - m*m, 0.0f);
        float s = g2[c] * rsqrtf(v + EPSV);
        sc2v[t*8+i] = s;
        sh2v[t*8+i] = fmaf(-m, s, b2[c]);
    }
    float s0a = 0.f, s1a = 0.f;
    for (int tile = blockIdx.x; tile < NPTS/16; tile += gridDim.x) {
        int p = tile*16 + sidx;
        unsigned int ahu[2][4], alu[2][4];
        #pragma unroll
        for (int t = 0; t < 2; t++) {
            f32x4 mx0 = *(const f32x4*)(y2max + (size_t)p*64 + t*32 + g*8);
            f32x4 mx1 = *(const f32x4*)(y2max + (size_t)p*64 + t*32 + g*8 + 4);
            f32x4 mn0 = *(const f32x4*)(y2min + (size_t)p*64 + t*32 + g*8);
            f32x4 mn1 = *(const f32x4*)(y2min + (size_t)p*64 + t*32 + g*8 + 4);
            float mval[8];
            #pragma unroll
            for (int i = 0; i < 4; i++) {
                float sc = sc2v[t*8+i];
                float pre = (sc >= 0.f) ? mx0[i] : mn0[i];
                mval[i] = fmaxf(fmaf(sc, pre, sh2v[t*8+i]), 0.0f);
                float sc2 = sc2v[t*8+4+i];
                float pre2 = (sc2 >= 0.f) ? mx1[i] : mn1[i];
                mval[4+i] = fmaxf(fmaf(sc2, pre2, sh2v[t*8+4+i]), 0.0f);
            }
            #pragma unroll
            for (int r = 0; r < 4; r++) split2(mval[2*r], mval[2*r+1], ahu[t][r], alu[t][r]);
        }
        f32x4 acc = (f32x4){0.f,0.f,0.f,0.f};
        #pragma unroll
        for (int t = 0; t < 2; t++) {
            FragU ah, al, Bh, Bl;
            ah.u = (u32x4){ahu[t][0], ahu[t][1], ahu[t][2], ahu[t][3]};
            al.u = (u32x4){alu[t][0], alu[t][1], alu[t][2], alu[t][3]};
            Bh.u = (u32x4){bh[t][0], bh[t][1], bh[t][2], bh[t][3]};
            Bl.u = (u32x4){bl[t][0], bl[t][1], bl[t][2], bl[t][3]};
            acc = __builtin_amdgcn_mfma_f32_16x16x32_bf16(ah.h, Bh.h, acc, 0, 0, 0);
            acc = __builtin_amdgcn_mfma_f32_16x16x32_bf16(ah.h, Bl.h, acc, 0, 0, 0);
            acc = __builtin_amdgcn_mfma_f32_16x16x32_bf16(al.h, Bh.h, acc, 0, 0, 0);
        }
        #pragma unroll
        for (int r = 0; r < 4; r++) {
            int po = tile*16 + g*4 + r;
            float v = acc[r];
            y3[(size_t)po*64 + ft*16 + sidx] = v;
            s0a += v;
            s1a = fmaf(v, v, s1a);
        }
    }
    s0a += __shfl_xor(s0a, 16, 64); s0a += __shfl_xor(s0a, 32, 64);
    s1a += __shfl_xor(s1a, 16, 64); s1a += __shfl_xor(s1a, 32, 64);
    __shared__ float r0[64], r1[64];
    if (l < 16) { r0[wv*16 + sidx] = s0a; r1[wv*16 + sidx] = s1a; }
    __syncthreads();
    int tid = threadIdx.x;
    if (tid < 64) {
        atomicAdd(&stats[SUM3 + tid], r0[tid]);
        atomicAdd(&stats[SSQ3 + tid], r1[tid]);
    }
}

// final: out = relu(bn3(y3)) in-place (layer 1 only).
__global__ void k6(float* y3, const float* stats, const float* go, const float* bo) {
    int i = blockIdx.x * 256 + threadIdx.x;
    int f = i & 63;
    const float inv = 1.0f / (float)NPTS;
    float m = stats[SUM3 + f] * inv;
    float v = fmaxf(stats[SSQ3 + f] * inv - m*m, 0.0f);
    float s = go[f] * rsqrtf(v + EPSV);
    float sh = fmaf(-m, s, bo[f]);
    y3[i] = fmaxf(fmaf(s, y3[i], sh), 0.0f);
}

extern "C" void kernel_launch(void* const* d_in, const int* in_sizes, int n_in,
                              void* d_out, int out_size, void* d_ws, size_t ws_size,
                              hipStream_t stream) {
    const float* xyz    = (const float*)d_in[0];
    const float* feats0 = (const float*)d_in[1];
    const int*   knn    = (const int*)d_in[2];
    const void*  empty  = d_in[3];
    float* ws = (float*)d_ws;
    const size_t N64 = (size_t)NPTS * 64;
    float* KA    = ws;
    float* QBA   = ws + N64;
    float* Y2MAX = ws + 2*N64;
    float* Y2MIN = ws + 3*N64;
    float* stats = ws + 4*N64;           // 2 x 512 floats
    float* wfold = stats + 1024;         // WFOLD_FLOATS
    uint8_t* mask = (uint8_t*)(wfold + WFOLD_FLOATS);
    float* out = (float*)d_out;

    hipMemsetAsync(stats, 0, 1024 * sizeof(float), stream);
    k_mask<<<NPTS/256, 256, 0, stream>>>((const uint32_t*)empty, mask);

    const float* const* p0 = (const float* const*)(d_in + 4);
    const float* const* p1 = (const float* const*)(d_in + 4 + 13);

    // ---- layer 0 ----
    {
        const float* const* p = p0;
        float* sl = stats;
        k0<<<16, 64, 0, stream>>>(p[0], p[1], p[2], p[3], p[4], wfold, 16);
        k1m<16, false><<<1024, 256, 0, stream>>>(feats0, xyz, p[4], wfold,
                                                 sl, p[11], p[12], KA, QBA);
        k2<<<2048, 256, 0, stream>>>(KA, QBA, knn, mask, sl);
        k4<<<2048, 256, 0, stream>>>(KA, QBA, knn, mask, p[7], p[5], p[6], sl, Y2MAX, Y2MIN);
        k5m<<<2048, 256, 0, stream>>>(Y2MAX, Y2MIN, p[10], p[8], p[9], sl, out);  // y3_0 -> d_out
    }
    // ---- layer 1 ----
    {
        const float* const* p = p1;
        float* sl = stats + 512;
        k0<<<64, 64, 0, stream>>>(p[0], p[1], p[2], p[3], p[4], wfold, 64);
        k1m<64, true><<<1024, 256, 0, stream>>>(out, xyz, p[4], wfold,
                                                stats, p0[11], p0[12], KA, QBA);
        k2<<<2048, 256, 0, stream>>>(KA, QBA, knn, mask, sl);
        k4<<<2048, 256, 0, stream>>>(KA, QBA, knn, mask, p[7], p[5], p[6], sl, Y2MAX, Y2MIN);
        k5m<<<2048, 256, 0, stream>>>(Y2MAX, Y2MIN, p[10], p[8], p[9], sl, out);  // y3_1 -> d_out
        k6<<<NPTS*64/256, 256, 0, stream>>>(out, sl, p[11], p[12]);               // in-place bn3
    }
}

// Round 9
// 608.742 us; speedup vs baseline: 1.3258x; 1.0003x over previous
//
#include <hip/hip_runtime.h>
#include <cstdint>

#define NPTS 65536
#define NS 16
#define EPSV 1e-5f

typedef __attribute__((ext_vector_type(8))) short bf16x8;
typedef __attribute__((ext_vector_type(4))) float f32x4;
typedef __attribute__((ext_vector_type(4))) unsigned int u32x4;
union FragU { u32x4 u; bf16x8 h; };

// per-layer stats block (512 floats each)
#define SUM1 0
#define SSQ1 64
#define SUM2 128
#define SSQ2 192
#define SUM3 256
#define SSQ3 320
// wfold region (floats)
#define WKAOF 0
#define WQBAOF 4096
#define BKAOF 8192
#define BQBAOF 8256
#define WFOLD_FLOATS 8320

// Permuted channel layout for KA/QBA rows (gather-coalescing):
// pos(c) = (t*2+(i>>2))*16 + g*4 + (i&3), c = t*32 + g*8 + i.
// Lane g reads its 16 channels as 4 x f32x4 at float offsets q*16 + g*4;
// the 4 g-lanes of one row jointly cover one full 64B line per instruction.
__device__ __forceinline__ int permc(int c) {
    int t = c >> 5, g = (c >> 3) & 3, i = c & 7;
    return (t*2 + (i>>2))*16 + g*4 + (i&3);
}

// truncation split of two floats into packed bf16 hi-pair / lo-pair (v_perm based).
__device__ __forceinline__ void split2(float e0, float e1, unsigned int& hi, unsigned int& lo) {
    unsigned int u0 = __float_as_uint(e0), u1 = __float_as_uint(e1);
    hi = __builtin_amdgcn_perm(u1, u0, 0x07060302u);
    float l0f = e0 - __uint_as_float(u0 & 0xFFFF0000u);
    float l1f = e1 - __uint_as_float(u1 & 0xFFFF0000u);
    lo = __builtin_amdgcn_perm(__float_as_uint(l1f), __float_as_uint(l0f), 0x07060302u);
}

__global__ void k_mask(const uint32_t* emp32, uint8_t* mask) {
    int bad = 0;
    for (int w = threadIdx.x; w < 1024; w += 256) bad |= (emp32[w] > 1u) ? 1 : 0;
    __shared__ int sbad[4];
    unsigned long long b = __ballot(bad != 0);
    if ((threadIdx.x & 63) == 0) sbad[threadIdx.x >> 6] = (b != 0ull) ? 1 : 0;
    __syncthreads();
    int flag = sbad[0] | sbad[1] | sbad[2] | sbad[3];
    int i = blockIdx.x * 256 + threadIdx.x;
    uint8_t mv;
    if (flag) mv = (((const uint8_t*)emp32)[i] != 0);
    else      mv = (emp32[i] != 0u);
    mask[i] = mv;
}

// Folded weights: Wka = wk @ A, Wqba = wq @ (B-A); biases likewise.
__global__ void k0(const float* wq, const float* bq, const float* wk, const float* bk,
                   const float* w1, float* wfold, int cin) {
    int f = threadIdx.x;
    int c = blockIdx.x;
    float a = 0.f, q = 0.f;
    for (int d = 0; d < 64; d++) {
        float A  = w1[d*64 + f];
        float Bm = w1[(67+d)*64 + f] - A;
        a = fmaf(wk[c*64 + d], A,  a);
        q = fmaf(wq[c*64 + d], Bm, q);
    }
    wfold[WKAOF  + c*64 + f] = a;
    wfold[WQBAOF + c*64 + f] = q;
    if (c == 0) {
        float ba = 0.f, bqv = 0.f;
        for (int d = 0; d < 64; d++) {
            float A  = w1[d*64 + f];
            float Bm = w1[(67+d)*64 + f] - A;
            ba  = fmaf(bk[d], A,  ba);
            bqv = fmaf(bq[d], Bm, bqv);
        }
        wfold[BKAOF  + f] = ba;
        wfold[BQBAOF + f] = bqv;
    }
}

// MFMA k1: [KA|QBA](n,128) = prebn(feats) @ Wcat(cin,128) + xyz @ Axyz(3,128) + bias.
// Output rows stored in PERMUTED channel layout (permc).
template<int CIN, bool PREBN>
__global__ void __launch_bounds__(256) k1m(const float* __restrict__ feats, const float* __restrict__ xyz,
                    const float* __restrict__ w1, const float* __restrict__ wfold,
                    const float* __restrict__ statsPrev, const float* __restrict__ goP,
                    const float* __restrict__ boP,
                    float* __restrict__ KA, float* __restrict__ QBA) {
    const int l = threadIdx.x & 63;
    const int wv = threadIdx.x >> 6;
    const int sidx = l & 15;
    const int g = l >> 4;
    const int col = sidx;
    constexpr int NT = (CIN == 64) ? 2 : 1;

    unsigned int bh[NT][2][4], bl[NT][2][4];
    #pragma unroll
    for (int t = 0; t < NT; t++)
    #pragma unroll
    for (int fl = 0; fl < 2; fl++) {
        int f128 = (wv*2 + fl)*16 + col;
        const float* W = (f128 < 64) ? (wfold + WKAOF) : (wfold + WQBAOF);
        int f = (f128 < 64) ? f128 : f128 - 64;
        #pragma unroll
        for (int r = 0; r < 4; r++) {
            int c0 = t*32 + g*8 + 2*r;
            float e0 = 0.f, e1 = 0.f;
            if (CIN == 64 || g < 2) {
                e0 = W[c0*64 + f];
                e1 = W[(c0+1)*64 + f];
            }
            split2(e0, e1, bh[t][fl][r], bl[t][fl][r]);
        }
    }
    unsigned int xbh[2][4], xbl[2][4];
    float biasf[2];
    int posO[2];   // permuted in-row position of this lane's output channel
    #pragma unroll
    for (int fl = 0; fl < 2; fl++) {
        int f128 = (wv*2 + fl)*16 + col;
        float A0, A1, A2;
        if (f128 < 64) {
            A0 = w1[64*64 + f128]; A1 = w1[65*64 + f128]; A2 = w1[66*64 + f128];
            biasf[fl] = wfold[BKAOF + f128];
            posO[fl] = permc(f128);
        } else {
            int f = f128 - 64;
            A0 = w1[131*64 + f] - w1[64*64 + f];
            A1 = w1[132*64 + f] - w1[65*64 + f];
            A2 = w1[133*64 + f] - w1[66*64 + f];
            biasf[fl] = wfold[BQBAOF + f];
            posO[fl] = permc(f);
        }
        split2(A0, A1, xbh[fl][0], xbl[fl][0]);
        split2(A2, 0.f, xbh[fl][1], xbl[fl][1]);
        xbh[fl][2] = 0; xbh[fl][3] = 0; xbl[fl][2] = 0; xbl[fl][3] = 0;
    }
    float scP[NT*8], shP[NT*8];
    if (PREBN) {
        const float invN = 1.0f / (float)NPTS;
        #pragma unroll
        for (int t = 0; t < NT; t++)
        #pragma unroll
        for (int i = 0; i < 8; i++) {
            int c = t*32 + g*8 + i;
            float m = statsPrev[SUM3 + c] * invN;
            float v = fmaxf(statsPrev[SSQ3 + c] * invN - m*m, 0.0f);
            float s = goP[c] * rsqrtf(v + EPSV);
            scP[t*8+i] = s;
            shP[t*8+i] = fmaf(-m, s, boP[c]);
        }
    }

    for (int tile = blockIdx.x; tile < NPTS/16; tile += gridDim.x) {
        int p = tile*16 + sidx;
        unsigned int ahu[NT][4], alu[NT][4];
        #pragma unroll
        for (int t = 0; t < NT; t++) {
            float xv[8];
            if (CIN == 64) {
                f32x4 a0 = *(const f32x4*)(feats + (size_t)p*64 + t*32 + g*8);
                f32x4 a1 = *(const f32x4*)(feats + (size_t)p*64 + t*32 + g*8 + 4);
                #pragma unroll
                for (int i = 0; i < 4; i++) { xv[i] = a0[i]; xv[4+i] = a1[i]; }
                if (PREBN) {
                    #pragma unroll
                    for (int i = 0; i < 8; i++)
                        xv[i] = fmaxf(fmaf(scP[t*8+i], xv[i], shP[t*8+i]), 0.0f);
                }
            } else {
                if (g < 2) {
                    f32x4 a0 = *(const f32x4*)(feats + (size_t)p*16 + g*8);
                    f32x4 a1 = *(const f32x4*)(feats + (size_t)p*16 + g*8 + 4);
                    #pragma unroll
                    for (int i = 0; i < 4; i++) { xv[i] = a0[i]; xv[4+i] = a1[i]; }
                } else {
                    #pragma unroll
                    for (int i = 0; i < 8; i++) xv[i] = 0.f;
                }
            }
            #pragma unroll
            for (int r = 0; r < 4; r++) split2(xv[2*r], xv[2*r+1], ahu[t][r], alu[t][r]);
        }
        unsigned int xah[4] = {0,0,0,0}, xal[4] = {0,0,0,0};
        if (g == 0) {
            float x0 = xyz[p*3], x1 = xyz[p*3+1], x2 = xyz[p*3+2];
            split2(x0, x1, xah[0], xal[0]);
            split2(x2, 0.f, xah[1], xal[1]);
        }
        f32x4 acc[2];
        #pragma unroll
        for (int fl = 0; fl < 2; fl++)
            acc[fl] = (f32x4){biasf[fl], biasf[fl], biasf[fl], biasf[fl]};
        #pragma unroll
        for (int t = 0; t < NT; t++) {
            FragU ah, al;
            ah.u = (u32x4){ahu[t][0], ahu[t][1], ahu[t][2], ahu[t][3]};
            al.u = (u32x4){alu[t][0], alu[t][1], alu[t][2], alu[t][3]};
            #pragma unroll
            for (int fl = 0; fl < 2; fl++) {
                FragU Bh, Bl;
                Bh.u = (u32x4){bh[t][fl][0], bh[t][fl][1], bh[t][fl][2], bh[t][fl][3]};
                Bl.u = (u32x4){bl[t][fl][0], bl[t][fl][1], bl[t][fl][2], bl[t][fl][3]};
                acc[fl] = __builtin_amdgcn_mfma_f32_16x16x32_bf16(ah.h, Bh.h, acc[fl], 0, 0, 0);
                acc[fl] = __builtin_amdgcn_mfma_f32_16x16x32_bf16(ah.h, Bl.h, acc[fl], 0, 0, 0);
                acc[fl] = __builtin_amdgcn_mfma_f32_16x16x32_bf16(al.h, Bh.h, acc[fl], 0, 0, 0);
            }
        }
        {
            FragU ah, al;
            ah.u = (u32x4){xah[0], xah[1], xah[2], xah[3]};
            al.u = (u32x4){xal[0], xal[1], xal[2], xal[3]};
            #pragma unroll
            for (int fl = 0; fl < 2; fl++) {
                FragU Bh, Bl;
                Bh.u = (u32x4){xbh[fl][0], xbh[fl][1], xbh[fl][2], xbh[fl][3]};
                Bl.u = (u32x4){xbl[fl][0], xbl[fl][1], xbl[fl][2], xbl[fl][3]};
                acc[fl] = __builtin_amdgcn_mfma_f32_16x16x32_bf16(ah.h, Bh.h, acc[fl], 0, 0, 0);
                acc[fl] = __builtin_amdgcn_mfma_f32_16x16x32_bf16(ah.h, Bl.h, acc[fl], 0, 0, 0);
                acc[fl] = __builtin_amdgcn_mfma_f32_16x16x32_bf16(al.h, Bh.h, acc[fl], 0, 0, 0);
            }
        }
        #pragma unroll
        for (int fl = 0; fl < 2; fl++) {
            int f128 = (wv*2 + fl)*16 + col;
            #pragma unroll
            for (int r = 0; r < 4; r++) {
                int po = tile*16 + g*4 + r;
                float v = acc[fl][r];
                if (f128 < 64) KA[(size_t)po*64 + posO[fl]] = v;
                else           QBA[(size_t)po*64 + posO[fl]] = v;
            }
        }
    }
}

// k2: stats of y1 over (n,s). Batch-2; PERMUTED layout -> each gather instr
// reads full 64B lines (4 g-lanes cover one line per row).
__global__ void __launch_bounds__(256) k2(const float* __restrict__ KA, const float* __restrict__ QBA,
                   const int* __restrict__ knn, const uint8_t* __restrict__ mask, float* stats) {
    const int l = threadIdx.x & 63;
    const int wv = threadIdx.x >> 6;
    const int s = l & 15;
    const int g = l >> 4;
    float s0[16], s1[16];
    #pragma unroll
    for (int i = 0; i < 16; i++) { s0[i] = 0.f; s1[i] = 0.f; }

    const int STR = gridDim.x * 8;
    for (int n0 = blockIdx.x * 8 + wv*2; n0 < NPTS; n0 += STR) {
        bool msk[2];
        f32x4 ka[2][4];
        #pragma unroll
        for (int u = 0; u < 2; u++) {
            int n = n0 + u;
            msk[u] = (mask[n] != 0);
            if (!msk[u]) {
                int j = knn[n*16 + s];
                const float* kap = KA + (size_t)j*64 + g*4;
                #pragma unroll
                for (int q = 0; q < 4; q++) ka[u][q] = *(const f32x4*)(kap + q*16);
            }
        }
        #pragma unroll
        for (int u = 0; u < 2; u++) {
            if (msk[u]) continue;
            int n = n0 + u;
            const float* qbp = QBA + (size_t)n*64 + g*4;
            #pragma unroll
            for (int q = 0; q < 4; q++) {
                f32x4 qb = *(const f32x4*)(qbp + q*16);
                #pragma unroll
                for (int e = 0; e < 4; e++) {
                    float y = ka[u][q][e] + qb[e];
                    s0[q*4+e] += y;
                    s1[q*4+e] = fmaf(y, y, s1[q*4+e]);
                }
            }
        }
    }
    #pragma unroll
    for (int i = 0; i < 16; i++) {
        #pragma unroll
        for (int d = 1; d < 16; d <<= 1) {
            s0[i] += __shfl_xor(s0[i], d, 64);
            s1[i] += __shfl_xor(s1[i], d, 64);
        }
    }
    __shared__ float r0[4][64], r1[4][64];
    if (s == 0) {
        #pragma unroll
        for (int q = 0; q < 4; q++)
        #pragma unroll
        for (int e = 0; e < 4; e++) {
            int c = (q>>1)*32 + g*8 + (q&1)*4 + e;   // inverse perm
            r0[wv][c] = s0[q*4+e];
            r1[wv][c] = s1[q*4+e];
        }
    }
    __syncthreads();
    int tid = threadIdx.x;
    if (tid < 64) {
        atomicAdd(&stats[SUM1 + tid], r0[0][tid]+r0[1][tid]+r0[2][tid]+r0[3][tid]);
        atomicAdd(&stats[SSQ1 + tid], r1[0][tid]+r1[1][tid]+r1[2][tid]+r1[3][tid]);
    }
}

// MFMA k4: batch-2 full-line gather (permuted layout) -> bn1+relu -> x1 @ w2,
// stats2 + per-(n,f) max/min.
__global__ void __launch_bounds__(256) k4(const float* __restrict__ KA, const float* __restrict__ QBA,
                   const int* __restrict__ knn, const uint8_t* __restrict__ mask,
                   const float* __restrict__ w2, const float* __restrict__ g1, const float* __restrict__ b1,
                   float* stats, float* __restrict__ y2max, float* __restrict__ y2min) {
    const int l    = threadIdx.x & 63;
    const int wv   = threadIdx.x >> 6;
    const int sidx = l & 15;
    const int g    = l >> 4;
    const int col  = sidx;

    float sc1v[16], sh1v[16];
    const float inv = 1.0f / ((float)NPTS * (float)NS);
    #pragma unroll
    for (int t = 0; t < 2; t++)
    #pragma unroll
    for (int i = 0; i < 8; i++) {
        int c = t*32 + g*8 + i;
        float m = stats[SUM1 + c] * inv;
        float v = fmaxf(stats[SSQ1 + c] * inv - m*m, 0.0f);
        float s = g1[c] * rsqrtf(v + EPSV);
        sc1v[t*8+i] = s;
        sh1v[t*8+i] = fmaf(-m, s, b1[c]);
    }

    unsigned int whu[2][4][4], wlu[2][4][4];
    #pragma unroll
    for (int t = 0; t < 2; t++)
    #pragma unroll
    for (int ft = 0; ft < 4; ft++)
    #pragma unroll
    for (int r = 0; r < 4; r++) {
        int k0i = t*32 + g*8 + 2*r;
        float e0 = w2[k0i*64 + ft*16 + col];
        float e1 = w2[(k0i+1)*64 + ft*16 + col];
        split2(e0, e1, whu[t][ft][r], wlu[t][ft][r]);
    }

    float s0t[4] = {0.f,0.f,0.f,0.f};
    float s1t[4] = {0.f,0.f,0.f,0.f};

    const int STR = gridDim.x * 8;
    for (int n0 = blockIdx.x * 8 + wv*2; n0 < NPTS; n0 += STR) {
        bool msk[2];
        f32x4 ka[2][4];
        #pragma unroll
        for (int u = 0; u < 2; u++) {
            int n = n0 + u;
            msk[u] = (mask[n] != 0);
            int j = knn[n*16 + sidx];
            const float* kap = KA + (size_t)j*64 + g*4;
            #pragma unroll
            for (int q = 0; q < 4; q++) ka[u][q] = *(const f32x4*)(kap + q*16);
        }
        #pragma unroll
        for (int u = 0; u < 2; u++) {
            int n = n0 + u;
            bool masked = msk[u];
            const float* qbp = QBA + (size_t)n*64 + g*4;
            f32x4 qq[4];
            #pragma unroll
            for (int q = 0; q < 4; q++) qq[q] = *(const f32x4*)(qbp + q*16);

            // logical x[t*8+i]: loaded reg (q = t*2 + (i>>2), r = i&3)
            float x[16];
            #pragma unroll
            for (int t = 0; t < 2; t++)
            #pragma unroll
            for (int i = 0; i < 8; i++) {
                int q = t*2 + (i>>2), r = i&3;
                float y = masked ? 0.f : (ka[u][q][r] + qq[q][r]);
                x[t*8+i] = fmaxf(fmaf(sc1v[t*8+i], y, sh1v[t*8+i]), 0.0f);
            }

            unsigned int ahu[2][4], alu[2][4];
            #pragma unroll
            for (int t = 0; t < 2; t++)
            #pragma unroll
            for (int r = 0; r < 4; r++)
                split2(x[t*8 + 2*r], x[t*8 + 2*r + 1], ahu[t][r], alu[t][r]);

            f32x4 acc[4];
            #pragma unroll
            for (int ft = 0; ft < 4; ft++) acc[ft] = (f32x4){0.f,0.f,0.f,0.f};

            #pragma unroll
            for (int t = 0; t < 2; t++) {
                FragU ah, al;
                ah.u = (u32x4){ahu[t][0], ahu[t][1], ahu[t][2], ahu[t][3]};
                al.u = (u32x4){alu[t][0], alu[t][1], alu[t][2], alu[t][3]};
                #pragma unroll
                for (int ft = 0; ft < 4; ft++) {
                    FragU bhf, blf;
                    bhf.u = (u32x4){whu[t][ft][0], whu[t][ft][1], whu[t][ft][2], whu[t][ft][3]};
                    blf.u = (u32x4){wlu[t][ft][0], wlu[t][ft][1], wlu[t][ft][2], wlu[t][ft][3]};
                    acc[ft] = __builtin_amdgcn_mfma_f32_16x16x32_bf16(ah.h, bhf.h, acc[ft], 0, 0, 0);
                    acc[ft] = __builtin_amdgcn_mfma_f32_16x16x32_bf16(ah.h, blf.h, acc[ft], 0, 0, 0);
                    acc[ft] = __builtin_amdgcn_mfma_f32_16x16x32_bf16(al.h, bhf.h, acc[ft], 0, 0, 0);
                }
            }

            float tmax[4], tmin[4];
            #pragma unroll
            for (int ft = 0; ft < 4; ft++) {
                f32x4 d = acc[ft];
                float lmax = fmaxf(fmaxf(d[0], d[1]), fmaxf(d[2], d[3]));
                float lmin = fminf(fminf(d[0], d[1]), fminf(d[2], d[3]));
                s0t[ft] += (d[0] + d[1]) + (d[2] + d[3]);
                s1t[ft] += fmaf(d[0],d[0], fmaf(d[1],d[1], fmaf(d[2],d[2], d[3]*d[3])));
                lmax = fmaxf(lmax, __shfl_xor(lmax, 16, 64));
                lmax = fmaxf(lmax, __shfl_xor(lmax, 32, 64));
                lmin = fminf(lmin, __shfl_xor(lmin, 16, 64));
                lmin = fminf(lmin, __shfl_xor(lmin, 32, 64));
                tmax[ft] = lmax; tmin[ft] = lmin;
            }
            float mx = (g==0) ? tmax[0] : (g==1) ? tmax[1] : (g==2) ? tmax[2] : tmax[3];
            float mn = (g==0) ? tmin[0] : (g==1) ? tmin[1] : (g==2) ? tmin[2] : tmin[3];
            y2max[(size_t)n*64 + l] = mx;
            y2min[(size_t)n*64 + l] = mn;
        }
    }

    #pragma unroll
    for (int ft = 0; ft < 4; ft++) {
        s0t[ft] += __shfl_xor(s0t[ft], 16, 64);
        s0t[ft] += __shfl_xor(s0t[ft], 32, 64);
        s1t[ft] += __shfl_xor(s1t[ft], 16, 64);
        s1t[ft] += __shfl_xor(s1t[ft], 32, 64);
    }
    float myS0 = (g==0) ? s0t[0] : (g==1) ? s0t[1] : (g==2) ? s0t[2] : s0t[3];
    float myS1 = (g==0) ? s1t[0] : (g==1) ? s1t[1] : (g==2) ? s1t[2] : s1t[3];
    __shared__ float red[8][64];
    red[wv][l] = myS0;
    red[4+wv][l] = myS1;
    __syncthreads();
    if (wv == 0) {
        atomicAdd(&stats[SUM2 + l], red[0][l]+red[1][l]+red[2][l]+red[3][l]);
        atomicAdd(&stats[SSQ2 + l], red[4][l]+red[5][l]+red[6][l]+red[7][l]);
    }
}

// MFMA k5: m = relu(bn2(max/min)); y3 = m @ wo; stats3.  (natural layout)
__global__ void __launch_bounds__(256) k5m(const float* __restrict__ y2max, const float* __restrict__ y2min,
                    const float* __restrict__ wo, const float* __restrict__ g2, const float* __restrict__ b2,
                    float* stats, float* __restrict__ y3) {
    const int l = threadIdx.x & 63;
    const int wv = threadIdx.x >> 6;
    const int sidx = l & 15;
    const int g = l >> 4;
    const int ft = wv;

    unsigned int bh[2][4], bl[2][4];
    #pragma unroll
    for (int t = 0; t < 2; t++)
    #pragma unroll
    for (int r = 0; r < 4; r++) {
        int c0 = t*32 + g*8 + 2*r;
        split2(wo[c0*64 + ft*16 + sidx], wo[(c0+1)*64 + ft*16 + sidx], bh[t][r], bl[t][r]);
    }
    float sc2v[16], sh2v[16];
    const float inv = 1.0f / ((float)NPTS * (float)NS);
    #pragma unroll
    for (int t = 0; t < 2; t++)
    #pragma unroll
    for (int i = 0; i < 8; i++) {
        int c = t*32 + g*8 + i;
        float m = stats[SUM2 + c] * inv;
        float v = fmaxf(stats[SSQ2 + c] * inv - m*m, 0.0f);
        float s = g2[c] * rsqrtf(v + EPSV);
        sc2v[t*8+i] = s;
        sh2v[t*8+i] = fmaf(-m, s, b2[c]);
    }
    float s0a = 0.f, s1a = 0.f;
    for (int tile = blockIdx.x; tile < NPTS/16; tile += gridDim.x) {
        int p = tile*16 + sidx;
        unsigned int ahu[2][4], alu[2][4];
        #pragma unroll
        for (int t = 0; t < 2; t++) {
            f32x4 mx0 = *(const f32x4*)(y2max + (size_t)p*64 + t*32 + g*8);
            f32x4 mx1 = *(const f32x4*)(y2max + (size_t)p*64 + t*32 + g*8 + 4);
            f32x4 mn0 = *(const f32x4*)(y2min + (size_t)p*64 + t*32 + g*8);
            f32x4 mn1 = *(const f32x4*)(y2min + (size_t)p*64 + t*32 + g*8 + 4);
            float mval[8];
            #pragma unroll
            for (int i = 0; i < 4; i++) {
                float sc = sc2v[t*8+i];
                float pre = (sc >= 0.f) ? mx0[i] : mn0[i];
                mval[i] = fmaxf(fmaf(sc, pre, sh2v[t*8+i]), 0.0f);
                float sc2 = sc2v[t*8+4+i];
                float pre2 = (sc2 >= 0.f) ? mx1[i] : mn1[i];
                mval[4+i] = fmaxf(fmaf(sc2, pre2, sh2v[t*8+4+i]), 0.0f);
            }
            #pragma unroll
            for (int r = 0; r < 4; r++) split2(mval[2*r], mval[2*r+1], ahu[t][r], alu[t][r]);
        }
        f32x4 acc = (f32x4){0.f,0.f,0.f,0.f};
        #pragma unroll
        for (int t = 0; t < 2; t++) {
            FragU ah, al, Bh, Bl;
            ah.u = (u32x4){ahu[t][0], ahu[t][1], ahu[t][2], ahu[t][3]};
            al.u = (u32x4){alu[t][0], alu[t][1], alu[t][2], alu[t][3]};
            Bh.u = (u32x4){bh[t][0], bh[t][1], bh[t][2], bh[t][3]};
            Bl.u = (u32x4){bl[t][0], bl[t][1], bl[t][2], bl[t][3]};
            acc = __builtin_amdgcn_mfma_f32_16x16x32_bf16(ah.h, Bh.h, acc, 0, 0, 0);
            acc = __builtin_amdgcn_mfma_f32_16x16x32_bf16(ah.h, Bl.h, acc, 0, 0, 0);
            acc = __builtin_amdgcn_mfma_f32_16x16x32_bf16(al.h, Bh.h, acc, 0, 0, 0);
        }
        #pragma unroll
        for (int r = 0; r < 4; r++) {
            int po = tile*16 + g*4 + r;
            float v = acc[r];
            y3[(size_t)po*64 + ft*16 + sidx] = v;
            s0a += v;
            s1a = fmaf(v, v, s1a);
        }
    }
    s0a += __shfl_xor(s0a, 16, 64); s0a += __shfl_xor(s0a, 32, 64);
    s1a += __shfl_xor(s1a, 16, 64); s1a += __shfl_xor(s1a, 32, 64);
    __shared__ float r0[64], r1[64];
    if (l < 16) { r0[wv*16 + sidx] = s0a; r1[wv*16 + sidx] = s1a; }
    __syncthreads();
    int tid = threadIdx.x;
    if (tid < 64) {
        atomicAdd(&stats[SUM3 + tid], r0[tid]);
        atomicAdd(&stats[SSQ3 + tid], r1[tid]);
    }
}

// final: out = relu(bn3(y3)) in-place (layer 1 only).
__global__ void k6(float* y3, const float* stats, const float* go, const float* bo) {
    int i = blockIdx.x * 256 + threadIdx.x;
    int f = i & 63;
    const float inv = 1.0f / (float)NPTS;
    float m = stats[SUM3 + f] * inv;
    float v = fmaxf(stats[SSQ3 + f] * inv - m*m, 0.0f);
    float s = go[f] * rsqrtf(v + EPSV);
    float sh = fmaf(-m, s, bo[f]);
    y3[i] = fmaxf(fmaf(s, y3[i], sh), 0.0f);
}

extern "C" void kernel_launch(void* const* d_in, const int* in_sizes, int n_in,
                              void* d_out, int out_size, void* d_ws, size_t ws_size,
                              hipStream_t stream) {
    const float* xyz    = (const float*)d_in[0];
    const float* feats0 = (const float*)d_in[1];
    const int*   knn    = (const int*)d_in[2];
    const void*  empty  = d_in[3];
    float* ws = (float*)d_ws;
    const size_t N64 = (size_t)NPTS * 64;
    float* KA    = ws;
    float* QBA   = ws + N64;
    float* Y2MAX = ws + 2*N64;
    float* Y2MIN = ws + 3*N64;
    float* stats = ws + 4*N64;           // 2 x 512 floats
    float* wfold = stats + 1024;         // WFOLD_FLOATS
    uint8_t* mask = (uint8_t*)(wfold + WFOLD_FLOATS);
    float* out = (float*)d_out;

    hipMemsetAsync(stats, 0, 1024 * sizeof(float), stream);
    k_mask<<<NPTS/256, 256, 0, stream>>>((const uint32_t*)empty, mask);

    const float* const* p0 = (const float* const*)(d_in + 4);
    const float* const* p1 = (const float* const*)(d_in + 4 + 13);

    // ---- layer 0 ----
    {
        const float* const* p = p0;
        float* sl = stats;
        k0<<<16, 64, 0, stream>>>(p[0], p[1], p[2], p[3], p[4], wfold, 16);
        k1m<16, false><<<1024, 256, 0, stream>>>(feats0, xyz, p[4], wfold,
                                                 sl, p[11], p[12], KA, QBA);
        k2<<<2048, 256, 0, stream>>>(KA, QBA, knn, mask, sl);
        k4<<<2048, 256, 0, stream>>>(KA, QBA, knn, mask, p[7], p[5], p[6], sl, Y2MAX, Y2MIN);
        k5m<<<2048, 256, 0, stream>>>(Y2MAX, Y2MIN, p[10], p[8], p[9], sl, out);  // y3_0 -> d_out
    }
    // ---- layer 1 ----
    {
        const float* const* p = p1;
        float* sl = stats + 512;
        k0<<<64, 64, 0, stream>>>(p[0], p[1], p[2], p[3], p[4], wfold, 64);
        k1m<64, true><<<1024, 256, 0, stream>>>(out, xyz, p[4], wfold,
                                                stats, p0[11], p0[12], KA, QBA);
        k2<<<2048, 256, 0, stream>>>(KA, QBA, knn, mask, sl);
        k4<<<2048, 256, 0, stream>>>(KA, QBA, knn, mask, p[7], p[5], p[6], sl, Y2MAX, Y2MIN);
        k5m<<<2048, 256, 0, stream>>>(Y2MAX, Y2MIN, p[10], p[8], p[9], sl, out);  // y3_1 -> d_out
        k6<<<NPTS*64/256, 256, 0, stream>>>(out, sl, p[11], p[12]);               // in-place bn3
    }
}

// Round 10
// 581.877 us; speedup vs baseline: 1.3871x; 1.0462x over previous
//
#include <hip/hip_runtime.h>
#include <cstdint>

#define NPTS 65536
#define NS 16
#define EPSV 1e-5f

typedef __attribute__((ext_vector_type(8))) short bf16x8;
typedef __attribute__((ext_vector_type(8))) unsigned short u16x8;
typedef __attribute__((ext_vector_type(4))) float f32x4;
typedef __attribute__((ext_vector_type(4))) unsigned int u32x4;
union FragU { u32x4 u; bf16x8 h; };

// per-layer stats block (512 floats each)
#define SUM1 0
#define SSQ1 64
#define SUM2 128
#define SSQ2 192
#define SUM3 256
#define SSQ3 320
// wfold region (floats)
#define WKAOF 0
#define WQBAOF 4096
#define BKAOF 8192
#define BQBAOF 8256
#define WFOLD_FLOATS 8320

// truncation split of two floats into packed bf16 hi-pair / lo-pair (v_perm based).
__device__ __forceinline__ void split2(float e0, float e1, unsigned int& hi, unsigned int& lo) {
    unsigned int u0 = __float_as_uint(e0), u1 = __float_as_uint(e1);
    hi = __builtin_amdgcn_perm(u1, u0, 0x07060302u);
    float l0f = e0 - __uint_as_float(u0 & 0xFFFF0000u);
    float l1f = e1 - __uint_as_float(u1 & 0xFFFF0000u);
    lo = __builtin_amdgcn_perm(__float_as_uint(l1f), __float_as_uint(l0f), 0x07060302u);
}

// fp32 -> bf16 round-to-nearest(-even-ish)
__device__ __forceinline__ unsigned short f2bf(float x) {
    unsigned int u = __float_as_uint(x);
    u += 0x7FFFu + ((u >> 16) & 1u);
    return (unsigned short)(u >> 16);
}
__device__ __forceinline__ float bf2f(unsigned short h) {
    return __uint_as_float(((unsigned int)h) << 16);
}

__global__ void k_mask(const uint32_t* emp32, uint8_t* mask) {
    int bad = 0;
    for (int w = threadIdx.x; w < 1024; w += 256) bad |= (emp32[w] > 1u) ? 1 : 0;
    __shared__ int sbad[4];
    unsigned long long b = __ballot(bad != 0);
    if ((threadIdx.x & 63) == 0) sbad[threadIdx.x >> 6] = (b != 0ull) ? 1 : 0;
    __syncthreads();
    int flag = sbad[0] | sbad[1] | sbad[2] | sbad[3];
    int i = blockIdx.x * 256 + threadIdx.x;
    uint8_t mv;
    if (flag) mv = (((const uint8_t*)emp32)[i] != 0);
    else      mv = (emp32[i] != 0u);
    mask[i] = mv;
}

// Folded weights: Wka = wk @ A, Wqba = wq @ (B-A); biases likewise.
__global__ void k0(const float* wq, const float* bq, const float* wk, const float* bk,
                   const float* w1, float* wfold, int cin) {
    int f = threadIdx.x;
    int c = blockIdx.x;
    float a = 0.f, q = 0.f;
    for (int d = 0; d < 64; d++) {
        float A  = w1[d*64 + f];
        float Bm = w1[(67+d)*64 + f] - A;
        a = fmaf(wk[c*64 + d], A,  a);
        q = fmaf(wq[c*64 + d], Bm, q);
    }
    wfold[WKAOF  + c*64 + f] = a;
    wfold[WQBAOF + c*64 + f] = q;
    if (c == 0) {
        float ba = 0.f, bqv = 0.f;
        for (int d = 0; d < 64; d++) {
            float A  = w1[d*64 + f];
            float Bm = w1[(67+d)*64 + f] - A;
            ba  = fmaf(bk[d], A,  ba);
            bqv = fmaf(bq[d], Bm, bqv);
        }
        wfold[BKAOF  + f] = ba;
        wfold[BQBAOF + f] = bqv;
    }
}

// MFMA k1: [KA|QBA](n,128) = prebn(feats) @ Wcat(cin,128) + xyz @ Axyz(3,128) + bias.
// KA stored as bf16 (natural layout, 128B rows); QBA fp32 natural.
template<int CIN, bool PREBN>
__global__ void __launch_bounds__(256) k1m(const float* __restrict__ feats, const float* __restrict__ xyz,
                    const float* __restrict__ w1, const float* __restrict__ wfold,
                    const float* __restrict__ statsPrev, const float* __restrict__ goP,
                    const float* __restrict__ boP,
                    unsigned short* __restrict__ KAb, float* __restrict__ QBA) {
    const int l = threadIdx.x & 63;
    const int wv = threadIdx.x >> 6;
    const int sidx = l & 15;
    const int g = l >> 4;
    const int col = sidx;
    constexpr int NT = (CIN == 64) ? 2 : 1;

    unsigned int bh[NT][2][4], bl[NT][2][4];
    #pragma unroll
    for (int t = 0; t < NT; t++)
    #pragma unroll
    for (int fl = 0; fl < 2; fl++) {
        int f128 = (wv*2 + fl)*16 + col;
        const float* W = (f128 < 64) ? (wfold + WKAOF) : (wfold + WQBAOF);
        int f = (f128 < 64) ? f128 : f128 - 64;
        #pragma unroll
        for (int r = 0; r < 4; r++) {
            int c0 = t*32 + g*8 + 2*r;
            float e0 = 0.f, e1 = 0.f;
            if (CIN == 64 || g < 2) {
                e0 = W[c0*64 + f];
                e1 = W[(c0+1)*64 + f];
            }
            split2(e0, e1, bh[t][fl][r], bl[t][fl][r]);
        }
    }
    unsigned int xbh[2][4], xbl[2][4];
    float biasf[2];
    #pragma unroll
    for (int fl = 0; fl < 2; fl++) {
        int f128 = (wv*2 + fl)*16 + col;
        float A0, A1, A2;
        if (f128 < 64) {
            A0 = w1[64*64 + f128]; A1 = w1[65*64 + f128]; A2 = w1[66*64 + f128];
            biasf[fl] = wfold[BKAOF + f128];
        } else {
            int f = f128 - 64;
            A0 = w1[131*64 + f] - w1[64*64 + f];
            A1 = w1[132*64 + f] - w1[65*64 + f];
            A2 = w1[133*64 + f] - w1[66*64 + f];
            biasf[fl] = wfold[BQBAOF + f];
        }
        split2(A0, A1, xbh[fl][0], xbl[fl][0]);
        split2(A2, 0.f, xbh[fl][1], xbl[fl][1]);
        xbh[fl][2] = 0; xbh[fl][3] = 0; xbl[fl][2] = 0; xbl[fl][3] = 0;
    }
    float scP[NT*8], shP[NT*8];
    if (PREBN) {
        const float invN = 1.0f / (float)NPTS;
        #pragma unroll
        for (int t = 0; t < NT; t++)
        #pragma unroll
        for (int i = 0; i < 8; i++) {
            int c = t*32 + g*8 + i;
            float m = statsPrev[SUM3 + c] * invN;
            float v = fmaxf(statsPrev[SSQ3 + c] * invN - m*m, 0.0f);
            float s = goP[c] * rsqrtf(v + EPSV);
            scP[t*8+i] = s;
            shP[t*8+i] = fmaf(-m, s, boP[c]);
        }
    }

    for (int tile = blockIdx.x; tile < NPTS/16; tile += gridDim.x) {
        int p = tile*16 + sidx;
        unsigned int ahu[NT][4], alu[NT][4];
        #pragma unroll
        for (int t = 0; t < NT; t++) {
            float xv[8];
            if (CIN == 64) {
                f32x4 a0 = *(const f32x4*)(feats + (size_t)p*64 + t*32 + g*8);
                f32x4 a1 = *(const f32x4*)(feats + (size_t)p*64 + t*32 + g*8 + 4);
                #pragma unroll
                for (int i = 0; i < 4; i++) { xv[i] = a0[i]; xv[4+i] = a1[i]; }
                if (PREBN) {
                    #pragma unroll
                    for (int i = 0; i < 8; i++)
                        xv[i] = fmaxf(fmaf(scP[t*8+i], xv[i], shP[t*8+i]), 0.0f);
                }
            } else {
                if (g < 2) {
                    f32x4 a0 = *(const f32x4*)(feats + (size_t)p*16 + g*8);
                    f32x4 a1 = *(const f32x4*)(feats + (size_t)p*16 + g*8 + 4);
                    #pragma unroll
                    for (int i = 0; i < 4; i++) { xv[i] = a0[i]; xv[4+i] = a1[i]; }
                } else {
                    #pragma unroll
                    for (int i = 0; i < 8; i++) xv[i] = 0.f;
                }
            }
            #pragma unroll
            for (int r = 0; r < 4; r++) split2(xv[2*r], xv[2*r+1], ahu[t][r], alu[t][r]);
        }
        unsigned int xah[4] = {0,0,0,0}, xal[4] = {0,0,0,0};
        if (g == 0) {
            float x0 = xyz[p*3], x1 = xyz[p*3+1], x2 = xyz[p*3+2];
            split2(x0, x1, xah[0], xal[0]);
            split2(x2, 0.f, xah[1], xal[1]);
        }
        f32x4 acc[2];
        #pragma unroll
        for (int fl = 0; fl < 2; fl++)
            acc[fl] = (f32x4){biasf[fl], biasf[fl], biasf[fl], biasf[fl]};
        #pragma unroll
        for (int t = 0; t < NT; t++) {
            FragU ah, al;
            ah.u = (u32x4){ahu[t][0], ahu[t][1], ahu[t][2], ahu[t][3]};
            al.u = (u32x4){alu[t][0], alu[t][1], alu[t][2], alu[t][3]};
            #pragma unroll
            for (int fl = 0; fl < 2; fl++) {
                FragU Bh, Bl;
                Bh.u = (u32x4){bh[t][fl][0], bh[t][fl][1], bh[t][fl][2], bh[t][fl][3]};
                Bl.u = (u32x4){bl[t][fl][0], bl[t][fl][1], bl[t][fl][2], bl[t][fl][3]};
                acc[fl] = __builtin_amdgcn_mfma_f32_16x16x32_bf16(ah.h, Bh.h, acc[fl], 0, 0, 0);
                acc[fl] = __builtin_amdgcn_mfma_f32_16x16x32_bf16(ah.h, Bl.h, acc[fl], 0, 0, 0);
                acc[fl] = __builtin_amdgcn_mfma_f32_16x16x32_bf16(al.h, Bh.h, acc[fl], 0, 0, 0);
            }
        }
        {
            FragU ah, al;
            ah.u = (u32x4){xah[0], xah[1], xah[2], xah[3]};
            al.u = (u32x4){xal[0], xal[1], xal[2], xal[3]};
            #pragma unroll
            for (int fl = 0; fl < 2; fl++) {
                FragU Bh, Bl;
                Bh.u = (u32x4){xbh[fl][0], xbh[fl][1], xbh[fl][2], xbh[fl][3]};
                Bl.u = (u32x4){xbl[fl][0], xbl[fl][1], xbl[fl][2], xbl[fl][3]};
                acc[fl] = __builtin_amdgcn_mfma_f32_16x16x32_bf16(ah.h, Bh.h, acc[fl], 0, 0, 0);
                acc[fl] = __builtin_amdgcn_mfma_f32_16x16x32_bf16(ah.h, Bl.h, acc[fl], 0, 0, 0);
                acc[fl] = __builtin_amdgcn_mfma_f32_16x16x32_bf16(al.h, Bh.h, acc[fl], 0, 0, 0);
            }
        }
        #pragma unroll
        for (int fl = 0; fl < 2; fl++) {
            int f128 = (wv*2 + fl)*16 + col;
            #pragma unroll
            for (int r = 0; r < 4; r++) {
                int po = tile*16 + g*4 + r;
                float v = acc[fl][r];
                if (f128 < 64) KAb[(size_t)po*64 + f128] = f2bf(v);
                else           QBA[(size_t)po*64 + (f128-64)] = v;
            }
        }
    }
}

// k2: stats of y1 over (n,s). Batch-4 bf16-KA gather (2x16B/row/lane, full lines).
__global__ void __launch_bounds__(256) k2(const unsigned short* __restrict__ KAb, const float* __restrict__ QBA,
                   const int* __restrict__ knn, const uint8_t* __restrict__ mask, float* stats) {
    const int l = threadIdx.x & 63;
    const int wv = threadIdx.x >> 6;
    const int s = l & 15;
    const int g = l >> 4;
    float s0[16], s1[16];
    #pragma unroll
    for (int i = 0; i < 16; i++) { s0[i] = 0.f; s1[i] = 0.f; }

    const int STR = gridDim.x * 16;
    for (int n0 = blockIdx.x * 16 + wv*4; n0 < NPTS; n0 += STR) {
        bool msk[4];
        u16x8 ka[4][2];
        #pragma unroll
        for (int u = 0; u < 4; u++) {
            int n = n0 + u;
            msk[u] = (mask[n] != 0);
            if (!msk[u]) {
                int j = knn[n*16 + s];
                const unsigned short* kp = KAb + (size_t)j*64;
                ka[u][0] = *(const u16x8*)(kp + g*8);
                ka[u][1] = *(const u16x8*)(kp + 32 + g*8);
            }
        }
        #pragma unroll
        for (int u = 0; u < 4; u++) {
            if (msk[u]) continue;
            int n = n0 + u;
            const float* qp = QBA + (size_t)n*64;
            f32x4 q0 = *(const f32x4*)(qp + g*8);
            f32x4 q1 = *(const f32x4*)(qp + g*8 + 4);
            f32x4 q2 = *(const f32x4*)(qp + 32 + g*8);
            f32x4 q3 = *(const f32x4*)(qp + 32 + g*8 + 4);
            #pragma unroll
            for (int t = 0; t < 2; t++)
            #pragma unroll
            for (int i = 0; i < 8; i++) {
                float kf = bf2f(ka[u][t][i]);
                float qv = t ? ((i < 4) ? q2[i] : q3[i-4])
                             : ((i < 4) ? q0[i] : q1[i-4]);
                float y = kf + qv;
                s0[t*8+i] += y;
                s1[t*8+i] = fmaf(y, y, s1[t*8+i]);
            }
        }
    }
    #pragma unroll
    for (int i = 0; i < 16; i++) {
        #pragma unroll
        for (int d = 1; d < 16; d <<= 1) {
            s0[i] += __shfl_xor(s0[i], d, 64);
            s1[i] += __shfl_xor(s1[i], d, 64);
        }
    }
    __shared__ float r0[4][64], r1[4][64];
    if (s == 0) {
        #pragma unroll
        for (int t = 0; t < 2; t++)
        #pragma unroll
        for (int i = 0; i < 8; i++) {
            int c = t*32 + g*8 + i;
            r0[wv][c] = s0[t*8+i];
            r1[wv][c] = s1[t*8+i];
        }
    }
    __syncthreads();
    int tid = threadIdx.x;
    if (tid < 64) {
        atomicAdd(&stats[SUM1 + tid], r0[0][tid]+r0[1][tid]+r0[2][tid]+r0[3][tid]);
        atomicAdd(&stats[SSQ1 + tid], r1[0][tid]+r1[1][tid]+r1[2][tid]+r1[3][tid]);
    }
}

// MFMA k4: batch-4 bf16-KA gather -> bn1+relu -> x1 @ w2 (3-term split),
// stats2 + per-(n,f) max/min.
__global__ void __launch_bounds__(256) k4(const unsigned short* __restrict__ KAb, const float* __restrict__ QBA,
                   const int* __restrict__ knn, const uint8_t* __restrict__ mask,
                   const float* __restrict__ w2, const float* __restrict__ g1, const float* __restrict__ b1,
                   float* stats, float* __restrict__ y2max, float* __restrict__ y2min) {
    const int l    = threadIdx.x & 63;
    const int wv   = threadIdx.x >> 6;
    const int sidx = l & 15;
    const int g    = l >> 4;
    const int col  = sidx;

    float sc1v[16], sh1v[16];
    const float inv = 1.0f / ((float)NPTS * (float)NS);
    #pragma unroll
    for (int t = 0; t < 2; t++)
    #pragma unroll
    for (int i = 0; i < 8; i++) {
        int c = t*32 + g*8 + i;
        float m = stats[SUM1 + c] * inv;
        float v = fmaxf(stats[SSQ1 + c] * inv - m*m, 0.0f);
        float s = g1[c] * rsqrtf(v + EPSV);
        sc1v[t*8+i] = s;
        sh1v[t*8+i] = fmaf(-m, s, b1[c]);
    }

    unsigned int whu[2][4][4], wlu[2][4][4];
    #pragma unroll
    for (int t = 0; t < 2; t++)
    #pragma unroll
    for (int ft = 0; ft < 4; ft++)
    #pragma unroll
    for (int r = 0; r < 4; r++) {
        int k0i = t*32 + g*8 + 2*r;
        float e0 = w2[k0i*64 + ft*16 + col];
        float e1 = w2[(k0i+1)*64 + ft*16 + col];
        split2(e0, e1, whu[t][ft][r], wlu[t][ft][r]);
    }

    float s0t[4] = {0.f,0.f,0.f,0.f};
    float s1t[4] = {0.f,0.f,0.f,0.f};

    const int STR = gridDim.x * 16;
    for (int n0 = blockIdx.x * 16 + wv*4; n0 < NPTS; n0 += STR) {
        bool msk[4];
        u16x8 ka[4][2];
        #pragma unroll
        for (int u = 0; u < 4; u++) {
            int n = n0 + u;
            msk[u] = (mask[n] != 0);
            int j = knn[n*16 + sidx];
            const unsigned short* kp = KAb + (size_t)j*64;
            ka[u][0] = *(const u16x8*)(kp + g*8);
            ka[u][1] = *(const u16x8*)(kp + 32 + g*8);
        }
        #pragma unroll
        for (int u = 0; u < 4; u++) {
            int n = n0 + u;
            bool masked = msk[u];
            const float* qp = QBA + (size_t)n*64;
            f32x4 q0 = *(const f32x4*)(qp + g*8);
            f32x4 q1 = *(const f32x4*)(qp + g*8 + 4);
            f32x4 q2 = *(const f32x4*)(qp + 32 + g*8);
            f32x4 q3 = *(const f32x4*)(qp + 32 + g*8 + 4);

            float x[16];
            #pragma unroll
            for (int t = 0; t < 2; t++)
            #pragma unroll
            for (int i = 0; i < 8; i++) {
                float kf = bf2f(ka[u][t][i]);
                float qv = t ? ((i < 4) ? q2[i] : q3[i-4])
                             : ((i < 4) ? q0[i] : q1[i-4]);
                float y = masked ? 0.f : (kf + qv);
                x[t*8+i] = fmaxf(fmaf(sc1v[t*8+i], y, sh1v[t*8+i]), 0.0f);
            }

            unsigned int ahu[2][4], alu[2][4];
            #pragma unroll
            for (int t = 0; t < 2; t++)
            #pragma unroll
            for (int r = 0; r < 4; r++)
                split2(x[t*8 + 2*r], x[t*8 + 2*r + 1], ahu[t][r], alu[t][r]);

            f32x4 acc[4];
            #pragma unroll
            for (int ft = 0; ft < 4; ft++) acc[ft] = (f32x4){0.f,0.f,0.f,0.f};

            #pragma unroll
            for (int t = 0; t < 2; t++) {
                FragU ah, al;
                ah.u = (u32x4){ahu[t][0], ahu[t][1], ahu[t][2], ahu[t][3]};
                al.u = (u32x4){alu[t][0], alu[t][1], alu[t][2], alu[t][3]};
                #pragma unroll
                for (int ft = 0; ft < 4; ft++) {
                    FragU bhf, blf;
                    bhf.u = (u32x4){whu[t][ft][0], whu[t][ft][1], whu[t][ft][2], whu[t][ft][3]};
                    blf.u = (u32x4){wlu[t][ft][0], wlu[t][ft][1], wlu[t][ft][2], wlu[t][ft][3]};
                    acc[ft] = __builtin_amdgcn_mfma_f32_16x16x32_bf16(ah.h, bhf.h, acc[ft], 0, 0, 0);
                    acc[ft] = __builtin_amdgcn_mfma_f32_16x16x32_bf16(ah.h, blf.h, acc[ft], 0, 0, 0);
                    acc[ft] = __builtin_amdgcn_mfma_f32_16x16x32_bf16(al.h, bhf.h, acc[ft], 0, 0, 0);
                }
            }

            float tmax[4], tmin[4];
            #pragma unroll
            for (int ft = 0; ft < 4; ft++) {
                f32x4 d = acc[ft];
                float lmax = fmaxf(fmaxf(d[0], d[1]), fmaxf(d[2], d[3]));
                float lmin = fminf(fminf(d[0], d[1]), fminf(d[2], d[3]));
                s0t[ft] += (d[0] + d[1]) + (d[2] + d[3]);
                s1t[ft] += fmaf(d[0],d[0], fmaf(d[1],d[1], fmaf(d[2],d[2], d[3]*d[3])));
                lmax = fmaxf(lmax, __shfl_xor(lmax, 16, 64));
                lmax = fmaxf(lmax, __shfl_xor(lmax, 32, 64));
                lmin = fminf(lmin, __shfl_xor(lmin, 16, 64));
                lmin = fminf(lmin, __shfl_xor(lmin, 32, 64));
                tmax[ft] = lmax; tmin[ft] = lmin;
            }
            float mx = (g==0) ? tmax[0] : (g==1) ? tmax[1] : (g==2) ? tmax[2] : tmax[3];
            float mn = (g==0) ? tmin[0] : (g==1) ? tmin[1] : (g==2) ? tmin[2] : tmin[3];
            y2max[(size_t)n*64 + l] = mx;
            y2min[(size_t)n*64 + l] = mn;
        }
    }

    #pragma unroll
    for (int ft = 0; ft < 4; ft++) {
        s0t[ft] += __shfl_xor(s0t[ft], 16, 64);
        s0t[ft] += __shfl_xor(s0t[ft], 32, 64);
        s1t[ft] += __shfl_xor(s1t[ft], 16, 64);
        s1t[ft] += __shfl_xor(s1t[ft], 32, 64);
    }
    float myS0 = (g==0) ? s0t[0] : (g==1) ? s0t[1] : (g==2) ? s0t[2] : s0t[3];
    float myS1 = (g==0) ? s1t[0] : (g==1) ? s1t[1] : (g==2) ? s1t[2] : s1t[3];
    __shared__ float red[8][64];
    red[wv][l] = myS0;
    red[4+wv][l] = myS1;
    __syncthreads();
    if (wv == 0) {
        atomicAdd(&stats[SUM2 + l], red[0][l]+red[1][l]+red[2][l]+red[3][l]);
        atomicAdd(&stats[SSQ2 + l], red[4][l]+red[5][l]+red[6][l]+red[7][l]);
    }
}

// MFMA k5: m = relu(bn2(max/min)); y3 = m @ wo; stats3.  (natural layout)
__global__ void __launch_bounds__(256) k5m(const float* __restrict__ y2max, const float* __restrict__ y2min,
                    const float* __restrict__ wo, const float* __restrict__ g2, const float* __restrict__ b2,
                    float* stats, float* __restrict__ y3) {
    const int l = threadIdx.x & 63;
    const int wv = threadIdx.x >> 6;
    const int sidx = l & 15;
    const int g = l >> 4;
    const int ft = wv;

    unsigned int bh[2][4], bl[2][4];
    #pragma unroll
    for (int t = 0; t < 2; t++)
    #pragma unroll
    for (int r = 0; r < 4; r++) {
        int c0 = t*32 + g*8 + 2*r;
        split2(wo[c0*64 + ft*16 + sidx], wo[(c0+1)*64 + ft*16 + sidx], bh[t][r], bl[t][r]);
    }
    float sc2v[16], sh2v[16];
    const float inv = 1.0f / ((float)NPTS * (float)NS);
    #pragma unroll
    for (int t = 0; t < 2; t++)
    #pragma unroll
    for (int i = 0; i < 8; i++) {
        int c = t*32 + g*8 + i;
        float m = stats[SUM2 + c] * inv;
        float v = fmaxf(stats[SSQ2 + c] * inv - m*m, 0.0f);
        float s = g2[c] * rsqrtf(v + EPSV);
        sc2v[t*8+i] = s;
        sh2v[t*8+i] = fmaf(-m, s, b2[c]);
    }
    float s0a = 0.f, s1a = 0.f;
    for (int tile = blockIdx.x; tile < NPTS/16; tile += gridDim.x) {
        int p = tile*16 + sidx;
        unsigned int ahu[2][4], alu[2][4];
        #pragma unroll
        for (int t = 0; t < 2; t++) {
            f32x4 mx0 = *(const f32x4*)(y2max + (size_t)p*64 + t*32 + g*8);
            f32x4 mx1 = *(const f32x4*)(y2max + (size_t)p*64 + t*32 + g*8 + 4);
            f32x4 mn0 = *(const f32x4*)(y2min + (size_t)p*64 + t*32 + g*8);
            f32x4 mn1 = *(const f32x4*)(y2min + (size_t)p*64 + t*32 + g*8 + 4);
            float mval[8];
            #pragma unroll
            for (int i = 0; i < 4; i++) {
                float sc = sc2v[t*8+i];
                float pre = (sc >= 0.f) ? mx0[i] : mn0[i];
                mval[i] = fmaxf(fmaf(sc, pre, sh2v[t*8+i]), 0.0f);
                float sc2 = sc2v[t*8+4+i];
                float pre2 = (sc2 >= 0.f) ? mx1[i] : mn1[i];
                mval[4+i] = fmaxf(fmaf(sc2, pre2, sh2v[t*8+4+i]), 0.0f);
            }
            #pragma unroll
            for (int r = 0; r < 4; r++) split2(mval[2*r], mval[2*r+1], ahu[t][r], alu[t][r]);
        }
        f32x4 acc = (f32x4){0.f,0.f,0.f,0.f};
        #pragma unroll
        for (int t = 0; t < 2; t++) {
            FragU ah, al, Bh, Bl;
            ah.u = (u32x4){ahu[t][0], ahu[t][1], ahu[t][2], ahu[t][3]};
            al.u = (u32x4){alu[t][0], alu[t][1], alu[t][2], alu[t][3]};
            Bh.u = (u32x4){bh[t][0], bh[t][1], bh[t][2], bh[t][3]};
            Bl.u = (u32x4){bl[t][0], bl[t][1], bl[t][2], bl[t][3]};
            acc = __builtin_amdgcn_mfma_f32_16x16x32_bf16(ah.h, Bh.h, acc, 0, 0, 0);
            acc = __builtin_amdgcn_mfma_f32_16x16x32_bf16(ah.h, Bl.h, acc, 0, 0, 0);
            acc = __builtin_amdgcn_mfma_f32_16x16x32_bf16(al.h, Bh.h, acc, 0, 0, 0);
        }
        #pragma unroll
        for (int r = 0; r < 4; r++) {
            int po = tile*16 + g*4 + r;
            float v = acc[r];
            y3[(size_t)po*64 + ft*16 + sidx] = v;
            s0a += v;
            s1a = fmaf(v, v, s1a);
        }
    }
    s0a += __shfl_xor(s0a, 16, 64); s0a += __shfl_xor(s0a, 32, 64);
    s1a += __shfl_xor(s1a, 16, 64); s1a += __shfl_xor(s1a, 32, 64);
    __shared__ float r0[64], r1[64];
    if (l < 16) { r0[wv*16 + sidx] = s0a; r1[wv*16 + sidx] = s1a; }
    __syncthreads();
    int tid = threadIdx.x;
    if (tid < 64) {
        atomicAdd(&stats[SUM3 + tid], r0[tid]);
        atomicAdd(&stats[SSQ3 + tid], r1[tid]);
    }
}

// final: out = relu(bn3(y3)) in-place (layer 1 only).
__global__ void k6(float* y3, const float* stats, const float* go, const float* bo) {
    int i = blockIdx.x * 256 + threadIdx.x;
    int f = i & 63;
    const float inv = 1.0f / (float)NPTS;
    float m = stats[SUM3 + f] * inv;
    float v = fmaxf(stats[SSQ3 + f] * inv - m*m, 0.0f);
    float s = go[f] * rsqrtf(v + EPSV);
    float sh = fmaf(-m, s, bo[f]);
    y3[i] = fmaxf(fmaf(s, y3[i], sh), 0.0f);
}

extern "C" void kernel_launch(void* const* d_in, const int* in_sizes, int n_in,
                              void* d_out, int out_size, void* d_ws, size_t ws_size,
                              hipStream_t stream) {
    const float* xyz    = (const float*)d_in[0];
    const float* feats0 = (const float*)d_in[1];
    const int*   knn    = (const int*)d_in[2];
    const void*  empty  = d_in[3];
    float* ws = (float*)d_ws;
    const size_t N64 = (size_t)NPTS * 64;
    unsigned short* KAb = (unsigned short*)ws;     // bf16 KA (uses half the region)
    float* QBA   = ws + N64;
    float* Y2MAX = ws + 2*N64;
    float* Y2MIN = ws + 3*N64;
    float* stats = ws + 4*N64;           // 2 x 512 floats
    float* wfold = stats + 1024;         // WFOLD_FLOATS
    uint8_t* mask = (uint8_t*)(wfold + WFOLD_FLOATS);
    float* out = (float*)d_out;

    hipMemsetAsync(stats, 0, 1024 * sizeof(float), stream);
    k_mask<<<NPTS/256, 256, 0, stream>>>((const uint32_t*)empty, mask);

    const float* const* p0 = (const float* const*)(d_in + 4);
    const float* const* p1 = (const float* const*)(d_in + 4 + 13);

    // ---- layer 0 ----
    {
        const float* const* p = p0;
        float* sl = stats;
        k0<<<16, 64, 0, stream>>>(p[0], p[1], p[2], p[3], p[4], wfold, 16);
        k1m<16, false><<<1024, 256, 0, stream>>>(feats0, xyz, p[4], wfold,
                                                 sl, p[11], p[12], KAb, QBA);
        k2<<<2048, 256, 0, stream>>>(KAb, QBA, knn, mask, sl);
        k4<<<2048, 256, 0, stream>>>(KAb, QBA, knn, mask, p[7], p[5], p[6], sl, Y2MAX, Y2MIN);
        k5m<<<2048, 256, 0, stream>>>(Y2MAX, Y2MIN, p[10], p[8], p[9], sl, out);  // y3_0 -> d_out
    }
    // ---- layer 1 ----
    {
        const float* const* p = p1;
        float* sl = stats + 512;
        k0<<<64, 64, 0, stream>>>(p[0], p[1], p[2], p[3], p[4], wfold, 64);
        k1m<64, true><<<1024, 256, 0, stream>>>(out, xyz, p[4], wfold,
                                                stats, p0[11], p0[12], KAb, QBA);
        k2<<<2048, 256, 0, stream>>>(KAb, QBA, knn, mask, sl);
        k4<<<2048, 256, 0, stream>>>(KAb, QBA, knn, mask, p[7], p[5], p[6], sl, Y2MAX, Y2MIN);
        k5m<<<2048, 256, 0, stream>>>(Y2MAX, Y2MIN, p[10], p[8], p[9], sl, out);  // y3_1 -> d_out
        k6<<<NPTS*64/256, 256, 0, stream>>>(out, sl, p[11], p[12]);               // in-place bn3
    }
}